// Round 14
// baseline (276.150 us; speedup 1.0000x reference)
//
#include <hip/hip_runtime.h>
#include <math.h>

#define NB 2
#define C1 128
#define C2 256
#define HH 128
#define WW 128
#define NPIX (HH*WW)
#define NHEADS 8
#define DH 16
#define NG 8

typedef unsigned short u16;
typedef _Float16 f16;
typedef __attribute__((ext_vector_type(8))) _Float16 h8_t;
typedef __attribute__((ext_vector_type(4))) _Float16 h4_t;
typedef __attribute__((ext_vector_type(4))) float f4_t;

__device__ __forceinline__ float sigmoidf_(float v) { return 1.f / (1.f + expf(-v)); }

// ---- NCHW fp32 (y|x) -> NHWC f16 cat + fused 2x2 avgpool (f16 NHWC) ----
__global__ __launch_bounds__(256) void splitcat2_k(const float* __restrict__ y,
                                                   const float* __restrict__ x,
                                                   f16* __restrict__ catf,
                                                   f16* __restrict__ ph) {
  __shared__ float tile[256][33];
  int b = blockIdx.z, c0 = blockIdx.y * 32, rp = blockIdx.x;
  int tid = threadIdx.x;
  const float* src = (c0 < 128) ? y : x;
  int cc0 = c0 & 127;
  const int pbase = rp * 256;
  for (int e = tid; e < 8192; e += 256) {
    int c = e >> 8, p = e & 255;
    tile[p][c] = src[((size_t)b * C1 + cc0 + c) * NPIX + pbase + p];
  }
  __syncthreads();
  for (int e = tid; e < 8192; e += 256) {
    int p = e >> 5, c = e & 31;
    catf[((size_t)b * NPIX + pbase + p) * C2 + c0 + c] = (f16)tile[p][c];
  }
  for (int e = tid; e < 2048; e += 256) {
    int pp = e >> 5, c = e & 31;
    float v = 0.25f * (tile[2 * pp][c] + tile[2 * pp + 1][c] +
                       tile[128 + 2 * pp][c] + tile[128 + 2 * pp + 1][c]);
    ph[((size_t)b * 4096 + rp * 64 + pp) * C2 + c0 + c] = (f16)v;
  }
}

// ---------------- fused weight prep + accumulator zero (one launch) ----------------
__device__ __forceinline__ void wtrans_h(const float* __restrict__ w, f16* __restrict__ w2,
                                         int OC, int OCR, int idx) {
  int t = idx / (256 * OCR);
  int rem = idx - t * 256 * OCR;
  int ic = rem / OCR;
  int oc = rem - ic * OCR;
  float v = (oc < OC) ? w[((size_t)oc * 256 + ic) * 9 + t] : 0.f;
  w2[((size_t)(t * 8 + (ic >> 5)) * OCR + oc) * 32 + (ic & 31)] = (f16)v;
}

__global__ __launch_bounds__(256) void wprep_all_k(
    const float* __restrict__ q_w, const float* __restrict__ pw_w,
    const float* __restrict__ kv_w, const float* __restrict__ proj_w,
    const float* __restrict__ dcn_w, const float* __restrict__ k2_w,
    const float* __restrict__ k3_w, const float* __restrict__ k4_w,
    f16* __restrict__ WQ, f16* __restrict__ WPW, f16* __restrict__ WKV,
    f16* __restrict__ WPJ, f16* __restrict__ WD,
    f16* __restrict__ W2K2, f16* __restrict__ W2K3, f16* __restrict__ W2K4,
    float* __restrict__ sacc) {
  int idx = blockIdx.x * 256 + threadIdx.x;
  if (idx < 16384) { WQ[idx] = (f16)q_w[idx]; return; }
  idx -= 16384;
  if (idx < 16384) { WPW[idx] = (f16)pw_w[idx]; return; }
  idx -= 16384;
  if (idx < 32768) { WKV[idx] = (f16)kv_w[idx]; return; }
  idx -= 32768;
  if (idx < 16384) { WPJ[idx] = (f16)proj_w[idx]; return; }
  idx -= 16384;
  if (idx < 20480) {
    int oc = idx / 160, k = idx - oc * 160;
    int t = k >> 4, ic = k & 15;
    WD[idx] = (t < 9) ? (f16)dcn_w[((size_t)oc * 16 + ic) * 9 + t] : (f16)0.f;
    return;
  }
  idx -= 20480;
  if (idx < 589824) { wtrans_h(k2_w, W2K2, 256, 256, idx); return; }
  idx -= 589824;
  if (idx < 589824) { wtrans_h(k3_w, W2K3, 256, 256, idx); return; }
  idx -= 589824;
  if (idx < 73728) { wtrans_h(k4_w, W2K4, 18, 32, idx); return; }
  idx -= 73728;
  if (idx < 4608) sacc[idx] = 0.f;
}

// ---------------- implicit-GEMM 3x3 conv, fp16 MFMA, dbuf LDS + depth-2 reg prefetch ----------------
template<int PXB, int OCB, int NPAN, int SPLITK, int NGB, int WO, int HO, int WI, int HI, int PAD,
         int OCTOT, int OCR, bool GATE, bool OUTF_NHWC, bool SWZ>
__global__ __launch_bounds__(256) void convh_k(
    const f16* __restrict__ inA, const f16* __restrict__ w2,
    const float* __restrict__ gy, const float* __restrict__ gx,
    const float* __restrict__ gB,
    float* __restrict__ outFp, size_t pstride,
    f16* __restrict__ outC) {
  constexpr int CIN = 256;
  constexpr int MF = (PXB == 64) ? 2 : ((OCB == 128) ? 4 : 2);
  constexpr int NF = (OCB == 128) ? 4 : 2;
  constexpr int GCN = 72 / SPLITK;
  __shared__ f16 lds_a[2][PXB * 32];
  __shared__ f16 lds_w[2][OCB * 32];
  const int b = blockIdx.z;
  const int oc0 = (blockIdx.y % NPAN) * OCB;
  const int kz = blockIdx.y / NPAN;
  const int gbase = kz * GCN;
  float* outF = outFp + (size_t)kz * pstride;
  int bidx = blockIdx.x;
  if (SWZ) bidx = (bidx & 7) * ((int)gridDim.x >> 3) + (bidx >> 3);
  const int px0 = bidx * PXB;
  const int tid = threadIdx.x;
  const int lane = tid & 63, wid = tid >> 6;
  const int wpx = (PXB == 64) ? ((wid & 1) * 32)
                              : ((OCB == 128) ? ((wid >> 1) * 64) : (wid * 32));
  const int woc = (PXB == 64) ? ((wid >> 1) * 64)
                              : ((OCB == 128) ? ((wid & 1) * 64) : 0);

  // A stager
  const int art = (PXB == 64) ? (tid >> 2) : (tid >> 1);
  const int aq = (PXB == 64) ? (tid & 3) : 0;
  const int shalf = (PXB == 64) ? 0 : (tid & 1);
  const int aopx = px0 + art;
  const int apy = aopx / WO, apxx = aopx % WO;
  const bool prow_ok = (aopx < HO * WO);
  int awo0, awo1;
  if (PXB == 64) {
    awo0 = art * 64 + ((aq ^ ((art >> 1) & 3)) << 4);
    awo1 = 0;
  } else {
    const int akey = (art >> 1) & 3;
    awo0 = art * 64 + (((shalf * 2 + 0) ^ akey) << 4);
    awo1 = art * 64 + (((shalf * 2 + 1) ^ akey) << 4);
  }
  // W stager
  const bool wact = (OCB == 128) ? true : (tid < OCB * 2);
  const int wrow = tid >> 1, whalf = tid & 1;
  const int wkey = (wrow >> 1) & 3;
  const int wwo0 = wrow * 64 + (((whalf * 2 + 0) ^ wkey) << 4);
  const int wwo1 = wrow * 64 + (((whalf * 2 + 1) ^ wkey) << 4);

  int aof[MF], wof[NF];
#pragma unroll
  for (int mf = 0; mf < MF; mf++) {
    int r = wpx + mf * 16 + (lane & 15);
    aof[mf] = r * 64 + (((lane >> 4) ^ ((r >> 1) & 3)) << 4);
  }
#pragma unroll
  for (int nf = 0; nf < NF; nf++) {
    int r = woc + nf * 16 + (lane & 15);
    wof[nf] = r * 64 + (((lane >> 4) ^ ((r >> 1) & 3)) << 4);
  }

  f4_t acc[MF][NF];
#pragma unroll
  for (int mf = 0; mf < MF; mf++)
#pragma unroll
    for (int nf = 0; nf < NF; nf++) { f4_t z = {0.f, 0.f, 0.f, 0.f}; acc[mf][nf] = z; }

  const size_t inb = (size_t)b * (HI * WI) * CIN;
  const size_t wg0 = (size_t)(oc0 + wrow) * 32 + (size_t)whalf * 16;

  // two named register sets (depth-2 prefetch; no runtime-indexed reg arrays)
  uint4 raA0, raA1, rwA0, rwA1;
  uint4 raB0, raB1, rwB0, rwB1;

#define LOAD_GC(gc, ra0, ra1, rw0, rw1)                                                    \
  {                                                                                        \
    const int t_ = (gc) >> 3, c_ = (gc) & 7;                                               \
    const int iy_ = apy + (t_ / 3) - PAD;                                                  \
    const int ix_ = apxx + (t_ % 3) - PAD;                                                 \
    const bool val_ = prow_ok && iy_ >= 0 && iy_ < HI && ix_ >= 0 && ix_ < WI;             \
    uint4 z_ = {0, 0, 0, 0};                                                               \
    ra0 = z_; ra1 = z_;                                                                    \
    if (val_) {                                                                            \
      if (PXB == 64) {                                                                     \
        ra0 = *(const uint4*)(inA + inb + (size_t)(iy_ * WI + ix_) * CIN + c_ * 32 + aq * 8); \
      } else {                                                                             \
        const uint4* p_ = (const uint4*)(inA + inb + (size_t)(iy_ * WI + ix_) * CIN + c_ * 32 + shalf * 16); \
        ra0 = p_[0];                                                                       \
        ra1 = p_[1];                                                                       \
      }                                                                                    \
    }                                                                                      \
    if (wact) {                                                                            \
      const uint4* q_ = (const uint4*)(w2 + (size_t)(gc) * OCR * 32 + wg0);                \
      rw0 = q_[0];                                                                         \
      rw1 = q_[1];                                                                         \
    }                                                                                      \
  }

#define STORE_GC(nb, ra0, ra1, rw0, rw1)                                                   \
  {                                                                                        \
    char* la_ = (char*)lds_a[nb];                                                          \
    char* lw_ = (char*)lds_w[nb];                                                          \
    *(uint4*)(la_ + awo0) = ra0;                                                           \
    if (PXB == 128) *(uint4*)(la_ + awo1) = ra1;                                           \
    if (wact) {                                                                            \
      *(uint4*)(lw_ + wwo0) = rw0;                                                         \
      *(uint4*)(lw_ + wwo1) = rw1;                                                         \
    }                                                                                      \
  }

#define COMPUTE(nb)                                                                        \
  {                                                                                        \
    const char* la_ = (const char*)lds_a[nb];                                              \
    const char* lw_ = (const char*)lds_w[nb];                                              \
    h8_t af_[MF], wf_[NF];                                                                 \
    _Pragma("unroll")                                                                      \
    for (int mf = 0; mf < MF; mf++) af_[mf] = *(const h8_t*)(la_ + aof[mf]);               \
    _Pragma("unroll")                                                                      \
    for (int nf = 0; nf < NF; nf++) wf_[nf] = *(const h8_t*)(lw_ + wof[nf]);               \
    _Pragma("unroll")                                                                      \
    for (int mf = 0; mf < MF; mf++)                                                        \
      _Pragma("unroll")                                                                    \
      for (int nf = 0; nf < NF; nf++)                                                      \
        acc[mf][nf] = __builtin_amdgcn_mfma_f32_16x16x32_f16(af_[mf], wf_[nf], acc[mf][nf], 0, 0, 0); \
  }

  // prologue: chunk 0 -> buf0; chunk 1 pending in set B
  LOAD_GC(gbase, raA0, raA1, rwA0, rwA1);
  STORE_GC(0, raA0, raA1, rwA0, rwA1);
  if (GCN > 1) LOAD_GC(gbase + 1, raB0, raB1, rwB0, rwB1);
  __syncthreads();
  for (int i = 0; i < GCN; i += 2) {
    // even sub-iter: compute buf0; prefetch chunk i+2 into A; store chunk i+1 (set B) -> buf1
    if (i + 2 < GCN) LOAD_GC(gbase + i + 2, raA0, raA1, rwA0, rwA1);
    COMPUTE(0);
    if (i + 1 < GCN) {
      STORE_GC(1, raB0, raB1, rwB0, rwB1);
      __syncthreads();
      // odd sub-iter: compute buf1; prefetch chunk i+3 into B; store chunk i+2 (set A) -> buf0
      if (i + 3 < GCN) LOAD_GC(gbase + i + 3, raB0, raB1, rwB0, rwB1);
      COMPUTE(1);
      if (i + 2 < GCN) STORE_GC(0, raA0, raA1, rwA0, rwA1);
      __syncthreads();
    }
  }
#undef LOAD_GC
#undef STORE_GC
#undef COMPUTE

  // epilogue: D row=(lane>>4)*4+r = px, col=lane&15 = oc  [m89-verified]
#pragma unroll
  for (int mf = 0; mf < MF; mf++) {
    const int pxb = px0 + wpx + mf * 16 + ((lane >> 4) << 2);
#pragma unroll
    for (int nf = 0; nf < NF; nf++) {
      const int oc = oc0 + woc + nf * 16 + (lane & 15);
      if (GATE) {
        const float* gp = (oc < 128) ? gy : gx;
        const size_t gbse = ((size_t)b * C1 + (oc & 127)) * NPIX;
        constexpr size_t gstride = (size_t)NB * 3844 * C2;
#pragma unroll
        for (int r = 0; r < 4; r++) {
          const int px = pxb + r;
          const int pyy = px >> 7, px2 = px & 127;
          const int iiy = (pyy * 62) >> 7, iix = (px2 * 62) >> 7;
          const size_t gi = ((size_t)b * 3844 + iiy * 62 + iix) * 256 + oc;
          float gv = gp[gbse + px];
#pragma unroll
          for (int pp = 0; pp < NGB; pp++) gv += gB[gi + (size_t)pp * gstride];
          float v = acc[mf][nf][r] * sigmoidf_(gv);
          outC[((size_t)b * NPIX + px) * C2 + oc] = (f16)v;
        }
      } else if (OUTF_NHWC) {
        if (oc < OCTOT) {
#pragma unroll
          for (int r = 0; r < 4; r++) {
            const int px = pxb + r;
            if (px < HO * WO)
              outF[((size_t)b * (HO * WO) + px) * OCTOT + oc] = acc[mf][nf][r];
          }
        }
      } else {
        if (pxb < HO * WO && oc < OCTOT)
          *(f4_t*)&outF[((size_t)b * OCTOT + oc) * (HO * WO) + pxb] = acc[mf][nf];
      }
    }
  }
}

// ---------------- sum NP split-K partial planes ----------------
template<int NP>
__global__ __launch_bounds__(256) void reduceN_k(const float* __restrict__ p,
                                                 float* __restrict__ o, int n4) {
  int i = blockIdx.x * 256 + threadIdx.x;
  if (i >= n4) return;
  const f4_t* v = (const f4_t*)p;
  f4_t r = v[i];
#pragma unroll
  for (int k = 1; k < NP; k++) {
    f4_t a = v[i + (size_t)k * n4];
    r[0] += a[0]; r[1] += a[1]; r[2] += a[2]; r[3] += a[3];
  }
  ((f4_t*)o)[i] = r;
}

// ---------------- 1x1 conv as fp16 MFMA GEMM, direct-global fragments ----------------
// OUTM: 0 = fp32 NCHW, 1 = f16 NHWC[128], 2 = f16 NCHW
template<int AS, int AOFF, bool BIAS, int OUTM>
__global__ __launch_bounds__(256) void gemm1x1_k(const f16* __restrict__ inA,
                                                 const f16* __restrict__ w,
                                                 const float* __restrict__ bias,
                                                 float* __restrict__ outF,
                                                 f16* __restrict__ outH) {
  const int b = blockIdx.z, nb0 = blockIdx.y * 128, px0 = blockIdx.x * 128;
  const int CoutTot = gridDim.y * 128;
  const int tid = threadIdx.x, lane = tid & 63, wid = tid >> 6;
  const int wpx = px0 + wid * 32;
  const int kslot = (lane >> 4) * 8;

  f4_t acc[2][8];
#pragma unroll
  for (int mf = 0; mf < 2; mf++)
#pragma unroll
    for (int nf = 0; nf < 8; nf++) { f4_t z = {0.f, 0.f, 0.f, 0.f}; acc[mf][nf] = z; }

  size_t arow[2];
#pragma unroll
  for (int mf = 0; mf < 2; mf++)
    arow[mf] = ((size_t)b * NPIX + wpx + mf * 16 + (lane & 15)) * AS + AOFF;
  size_t wrow[8];
#pragma unroll
  for (int nf = 0; nf < 8; nf++)
    wrow[nf] = (size_t)(nb0 + nf * 16 + (lane & 15)) * 128;

#pragma unroll
  for (int ks = 0; ks < 4; ks++) {
    const int ko = ks * 32 + kslot;
    h8_t a[2], bw[8];
#pragma unroll
    for (int mf = 0; mf < 2; mf++) a[mf] = *(const h8_t*)(inA + arow[mf] + ko);
#pragma unroll
    for (int nf = 0; nf < 8; nf++) bw[nf] = *(const h8_t*)(w + wrow[nf] + ko);
#pragma unroll
    for (int mf = 0; mf < 2; mf++)
#pragma unroll
      for (int nf = 0; nf < 8; nf++)
        acc[mf][nf] = __builtin_amdgcn_mfma_f32_16x16x32_f16(a[mf], bw[nf], acc[mf][nf], 0, 0, 0);
  }

#pragma unroll
  for (int mf = 0; mf < 2; mf++) {
    const int pxq = wpx + mf * 16 + (lane >> 4) * 4;
#pragma unroll
    for (int nf = 0; nf < 8; nf++) {
      const int oc = nb0 + nf * 16 + (lane & 15);
      f4_t v = acc[mf][nf];
      if (BIAS) {
        float bv = bias[oc];
        v[0] += bv; v[1] += bv; v[2] += bv; v[3] += bv;
      }
      if (OUTM == 1) {
#pragma unroll
        for (int r = 0; r < 4; r++)
          outH[((size_t)b * NPIX + pxq + r) * 128 + oc] = (f16)v[r];
      } else if (OUTM == 2) {
        h4_t o;
#pragma unroll
        for (int r = 0; r < 4; r++) o[r] = (f16)v[r];
        *(h4_t*)&outH[((size_t)b * CoutTot + oc) * NPIX + pxq] = o;
      } else {
        *(f4_t*)&outF[((size_t)b * CoutTot + oc) * NPIX + pxq] = v;
      }
    }
  }
}

// ---------------- fused modulated-deform-conv: NHWC f16 gather + grouped MFMA ----------------
__global__ __launch_bounds__(256) void dgemm_k(const f16* __restrict__ catf,
                                               const float* __restrict__ offs,
                                               const f16* __restrict__ wd,
                                               const float* __restrict__ dbias,
                                               f16* __restrict__ feat) {
  const int b = blockIdx.z, g = blockIdx.y;
  const int px0 = blockIdx.x * 128;
  const int tid = threadIdx.x;
  const int lane = tid & 63, wid = tid >> 6;
  const int chunk = lane >> 4;
  const int thalf = chunk >> 1;
  const int ic0 = (chunk & 1) * 8;
  const f16* yb = catf + (size_t)b * NPIX * C2;
  const float* ob = offs + (size_t)b * 18 * NPIX;

  int pm[2];
  float pyb[2], pxb2[2];
#pragma unroll
  for (int mf = 0; mf < 2; mf++) {
    pm[mf] = px0 + wid * 32 + mf * 16 + (lane & 15);
    pyb[mf] = (float)(pm[mf] >> 7);
    pxb2[mf] = (float)(pm[mf] & 127);
  }

  f4_t acc[2];
  { f4_t z = {0.f, 0.f, 0.f, 0.f}; acc[0] = z; acc[1] = z; }

  const size_t wbase = (size_t)(g * 16 + (lane & 15)) * 160;
#pragma unroll
  for (int s = 0; s < 5; s++) {
    h8_t ah[2];
#pragma unroll
    for (int mf = 0; mf < 2; mf++) {
      int t = 2 * s + thalf;
      int teff = t > 8 ? 8 : t;
      float dy = ob[(size_t)(2 * teff) * NPIX + pm[mf]];
      float dx = ob[(size_t)(2 * teff + 1) * NPIX + pm[mf]];
      float mk = sigmoidf_(ob[(size_t)teff * NPIX + pm[mf]]);
      int ky = teff / 3, kx = teff - 3 * ky;
      float pyf = pyb[mf] - 1.f + (float)ky + dy;
      float pxf = pxb2[mf] - 1.f + (float)kx + dx;
      float y0f = floorf(pyf), x0f = floorf(pxf);
      float fy = pyf - y0f, fx = pxf - x0f;
      int y0 = (int)y0f, x0 = (int)x0f;
      int y1 = y0 + 1, x1 = x0 + 1;
      float w00 = (1.f - fy) * (1.f - fx) * mk;
      float w01 = (1.f - fy) * fx * mk;
      float w10 = fy * (1.f - fx) * mk;
      float w11 = fy * fx * mk;
      bool vy0 = (y0 >= 0 && y0 < HH), vy1 = (y1 >= 0 && y1 < HH);
      bool vx0 = (x0 >= 0 && x0 < WW), vx1 = (x1 >= 0 && x1 < WW);
      if (!(vy0 && vx0)) w00 = 0.f;
      if (!(vy0 && vx1)) w01 = 0.f;
      if (!(vy1 && vx0)) w10 = 0.f;
      if (!(vy1 && vx1)) w11 = 0.f;
      int cy0 = min(max(y0, 0), HH - 1), cy1 = min(max(y1, 0), HH - 1);
      int cx0 = min(max(x0, 0), WW - 1), cx1 = min(max(x1, 0), WW - 1);
      const f16* p00 = yb + (size_t)(cy0 * WW + cx0) * C2 + g * 16 + ic0;
      const f16* p01 = yb + (size_t)(cy0 * WW + cx1) * C2 + g * 16 + ic0;
      const f16* p10 = yb + (size_t)(cy1 * WW + cx0) * C2 + g * 16 + ic0;
      const f16* p11 = yb + (size_t)(cy1 * WW + cx1) * C2 + g * 16 + ic0;
      h8_t a00 = *(const h8_t*)p00;
      h8_t a01 = *(const h8_t*)p01;
      h8_t a10 = *(const h8_t*)p10;
      h8_t a11 = *(const h8_t*)p11;
      h8_t hh;
#pragma unroll
      for (int j = 0; j < 8; j++) {
        float sv = w00 * (float)a00[j] + w01 * (float)a01[j] +
                   w10 * (float)a10[j] + w11 * (float)a11[j];
        hh[j] = (f16)sv;
      }
      ah[mf] = hh;
    }
    h8_t wv = *(const h8_t*)(wd + wbase + s * 32 + chunk * 8);
#pragma unroll
    for (int mf = 0; mf < 2; mf++)
      acc[mf] = __builtin_amdgcn_mfma_f32_16x16x32_f16(ah[mf], wv, acc[mf], 0, 0, 0);
  }

  const int oc = g * 16 + (lane & 15);
  const float bv = dbias[oc];
#pragma unroll
  for (int mf = 0; mf < 2; mf++) {
    const int pxq = px0 + wid * 32 + mf * 16 + (lane >> 4) * 4;
#pragma unroll
    for (int r = 0; r < 4; r++) {
      float v = fmaxf(acc[mf][r] + bv, 0.f);
      feat[((size_t)b * NPIX + pxq + r) * 128 + oc] = (f16)v;
    }
  }
}

// ---------------- depthwise 3x3, pad=1, f16 NCHW in/out, x8 vectorized ----------------
__global__ __launch_bounds__(256) void dw3x3h_k(const f16* __restrict__ in,
                                                const float* __restrict__ w,
                                                f16* __restrict__ out, int Cc) {
  int i8 = blockIdx.x * 256 + threadIdx.x;
  int total8 = NB * Cc * (NPIX / 8);
  if (i8 >= total8) return;
  int n8 = i8 & (NPIX / 8 - 1);
  int bc = i8 >> 11;
  int c = bc % Cc;
  int n = n8 << 3;
  int yy = n >> 7, xx = n & 127;
  const f16* p = in + (size_t)bc * NPIX;
  const float* wc = w + c * 9;
  float acc[8] = {0.f, 0.f, 0.f, 0.f, 0.f, 0.f, 0.f, 0.f};
#pragma unroll
  for (int ky = 0; ky < 3; ky++) {
    int iy = yy + ky - 1;
    if (iy < 0 || iy >= HH) continue;
    const f16* row = p + iy * WW;
    float v[10];
    v[0] = (xx > 0) ? (float)row[xx - 1] : 0.f;
    h8_t m = *(const h8_t*)(row + xx);
#pragma unroll
    for (int j = 0; j < 8; j++) v[j + 1] = (float)m[j];
    v[9] = (xx + 8 < WW) ? (float)row[xx + 8] : 0.f;
#pragma unroll
    for (int kx = 0; kx < 3; kx++) {
      float wv = wc[ky * 3 + kx];
#pragma unroll
      for (int j = 0; j < 8; j++) acc[j] += wv * v[j + kx];
    }
  }
  h8_t o;
#pragma unroll
  for (int j = 0; j < 8; j++) o[j] = (f16)acc[j];
  *(h8_t*)&out[(size_t)bc * NPIX + n] = o;
}

// ---------------- attention Gram (Q·K^T 16x16 over N=16384) via fp16 MFMA ----------------
__global__ __launch_bounds__(256) void gram_k(const f16* __restrict__ qbuf,
                                              const f16* __restrict__ kvbuf,
                                              float* __restrict__ s_acc,
                                              float* __restrict__ qss,
                                              float* __restrict__ kss) {
  int b = blockIdx.z, h = blockIdx.y;
  int tid = threadIdx.x, lane = tid & 63, wid = tid >> 6;
  int r = lane & 15, ks = lane >> 4;
  const f16* qb = qbuf + ((size_t)b * C1 + h * DH + r) * NPIX;
  const f16* kb = kvbuf + ((size_t)b * C2 + h * DH + r) * NPIX;
  int n0 = (blockIdx.x * 4 + wid) * 512;
  f4_t acc = {0.f, 0.f, 0.f, 0.f};
  float q2 = 0.f, k2 = 0.f;
  for (int s = 0; s < 16; s++) {
    int k = n0 + s * 32 + ks * 8;
    h8_t qv = *(const h8_t*)(qb + k);
    h8_t kv = *(const h8_t*)(kb + k);
#pragma unroll
    for (int j = 0; j < 8; j++) {
      float qf = (float)qv[j], kf = (float)kv[j];
      q2 += qf * qf;
      k2 += kf * kf;
    }
    acc = __builtin_amdgcn_mfma_f32_16x16x32_f16(qv, kv, acc, 0, 0, 0);
  }
  int bh = b * NHEADS + h;
#pragma unroll
  for (int rr = 0; rr < 4; rr++)
    atomicAdd(&s_acc[((size_t)bh * 16 + ks * 4 + rr) * 16 + r], acc[rr]);
  q2 += __shfl_xor(q2, 16);
  q2 += __shfl_xor(q2, 32);
  k2 += __shfl_xor(k2, 16);
  k2 += __shfl_xor(k2, 32);
  if (ks == 0) {
    atomicAdd(&qss[bh * 16 + r], q2);
    atomicAdd(&kss[bh * 16 + r], k2);
  }
}

// ---------------- attention: fused softmax + (attn @ v) -> NHWC f16 ----------------
__global__ __launch_bounds__(256) void attnout_k(const float* __restrict__ s_acc,
                                                 const float* __restrict__ qss,
                                                 const float* __restrict__ kss,
                                                 const float* __restrict__ temp,
                                                 const f16* __restrict__ kvbuf,
                                                 f16* __restrict__ outA) {
  __shared__ float S[16][17];
  __shared__ float A[16][17];
  __shared__ float qn[16], kn[16];
  int b = blockIdx.z, h = blockIdx.y;
  int tid = threadIdx.x;
  int bh = b * NHEADS + h;
  int dd = tid & 15, cc = tid >> 4;
  if (tid < 16) {
    qn[tid] = fmaxf(sqrtf(qss[bh * 16 + tid]), 1e-12f);
    kn[tid] = fmaxf(sqrtf(kss[bh * 16 + tid]), 1e-12f);
  }
  __syncthreads();
  float t = temp[h];
  float s = s_acc[((size_t)bh * 16 + cc) * 16 + dd] / (qn[cc] * kn[dd]) * t;
  S[cc][dd] = s;
  __syncthreads();
  float mx = -1e30f;
#pragma unroll
  for (int j = 0; j < 16; j++) mx = fmaxf(mx, S[cc][j]);
  float sum = 0.f;
#pragma unroll
  for (int j = 0; j < 16; j++) sum += expf(S[cc][j] - mx);
  A[cc][dd] = expf(s - mx) / sum;
  __syncthreads();

  int n = blockIdx.x * 256 + tid;
  const f16* vb = kvbuf + ((size_t)b * C2 + C1 + h * DH) * NPIX;
  float acc[16];
#pragma unroll
  for (int c = 0; c < 16; c++) acc[c] = 0.f;
#pragma unroll
  for (int d = 0; d < 16; d++) {
    float vv = (float)vb[(size_t)d * NPIX + n];
#pragma unroll
    for (int c = 0; c < 16; c++) acc[c] += A[c][d] * vv;
  }
  h8_t o0, o1;
#pragma unroll
  for (int c = 0; c < 8; c++) {
    o0[c] = (f16)acc[c];
    o1[c] = (f16)acc[8 + c];
  }
  size_t base = ((size_t)b * NPIX + n) * 128 + h * 16;
  *(h8_t*)(outA + base) = o0;
  *(h8_t*)(outA + base + 8) = o1;
}

extern "C" void kernel_launch(void* const* d_in, const int* in_sizes, int n_in,
                              void* d_out, int out_size, void* d_ws, size_t ws_size,
                              hipStream_t stream) {
  const float* x = (const float*)d_in[0];
  const float* y = (const float*)d_in[1];
  const float* q_w = (const float*)d_in[2];
  const float* qd_w = (const float*)d_in[3];
  const float* kv_w = (const float*)d_in[4];
  const float* kvd_w = (const float*)d_in[5];
  const float* proj_w = (const float*)d_in[6];
  const float* temperature = (const float*)d_in[7];
  const float* k2_w = (const float*)d_in[8];
  const float* k3_w = (const float*)d_in[9];
  const float* k4_w = (const float*)d_in[10];
  const float* dcn_w = (const float*)d_in[11];
  const float* dcn_b = (const float*)d_in[12];
  const float* pw_w = (const float*)d_in[13];
  const float* pw_b = (const float*)d_in[14];
  float* out = (float*)d_out;

  char* ws = (char*)d_ws;
  size_t off = 0;
  auto alloc = [&](size_t nbytes) {
    char* p = ws + off;
    off += (nbytes + 255) & ~(size_t)255;
    return p;
  };
  f16* CATF = (f16*)alloc((size_t)NB * NPIX * C2 * 2);
  f16* PH = (f16*)alloc((size_t)NB * 4096 * C2 * 2);
  float* A2 = (float*)alloc((size_t)4 * NB * 3844 * C2 * 4);
  f16* OUT3 = (f16*)alloc((size_t)NB * NPIX * C2 * 2);
  float* OF8P = (float*)alloc((size_t)8 * NB * 18 * NPIX * 4);
  float* OFFS = (float*)alloc((size_t)NB * 18 * NPIX * 4);
  f16* FEAT = (f16*)alloc((size_t)NB * NPIX * C1 * 2);
  f16* AL = (f16*)alloc((size_t)NB * NPIX * C1 * 2);
  f16* QbH = (f16*)alloc((size_t)NB * C1 * NPIX * 2);
  f16* W2K2 = (f16*)alloc((size_t)72 * 256 * 32 * 2);
  f16* W2K3 = (f16*)alloc((size_t)72 * 256 * 32 * 2);
  f16* W2K4 = (f16*)alloc((size_t)72 * 32 * 32 * 2);
  f16* WD = (f16*)alloc((size_t)128 * 160 * 2);
  f16* WQ = (f16*)alloc((size_t)128 * 128 * 2);
  f16* WPW = (f16*)alloc((size_t)128 * 128 * 2);
  f16* WKV = (f16*)alloc((size_t)256 * 128 * 2);
  f16* WPJ = (f16*)alloc((size_t)128 * 128 * 2);
  float* SACC = (float*)alloc((size_t)(NB * NHEADS * 256 + 512) * 4);
  float* QSS = SACC + NB * NHEADS * 256;
  float* KSS = QSS + 256;

  // region reuse (lifetimes)
  f16* QT1H = OUT3;             // q 1x1 out (dead before k3 writes OUT3)
  f16* KV1H = (f16*)A2;         // kv 1x1 out (A2 dead after k3's gate)
  f16* KVbH = OUT3;             // kv dw out (OUT3 dead after k4)
  f16* AO = FEAT;               // attn out (FEAT dead after pw)

  dim3 blk(256);

  wprep_all_k<<<dim3(5314), blk, 0, stream>>>(q_w, pw_w, kv_w, proj_w, dcn_w, k2_w, k3_w, k4_w,
                                              WQ, WPW, WKV, WPJ, WD, W2K2, W2K3, W2K4, SACC);

  splitcat2_k<<<dim3(64, C2 / 32, NB), blk, 0, stream>>>(y, x, CATF, PH);

  // q path
  gemm1x1_k<C2, C1, false, 2><<<dim3(NPIX / 128, 1, NB), blk, 0, stream>>>(
      CATF, WQ, nullptr, nullptr, QT1H);
  dw3x3h_k<<<dim3(NB * C1 * (NPIX / 8) / 256), blk, 0, stream>>>(QT1H, qd_w, QbH, C1);

  // offset head (fp16 MFMA, depth-2 prefetch)
  convh_k<128, 128, 2, 4, 0, 62, 62, 64, 64, 0, 256, 256, false, true, false>
      <<<dim3(31, 8, NB), blk, 0, stream>>>(PH, W2K2, nullptr, nullptr, nullptr,
                                            A2, (size_t)NB * 3844 * C2, nullptr);
  convh_k<64, 128, 2, 1, 4, 128, 128, 128, 128, 1, 256, 256, true, false, true>
      <<<dim3(256, 2, NB), blk, 0, stream>>>(CATF, W2K3, y, x, A2, nullptr, 0, OUT3);
  convh_k<128, 32, 1, 8, 0, 128, 128, 128, 128, 1, 18, 32, false, false, true>
      <<<dim3(128, 8, NB), blk, 0, stream>>>(OUT3, W2K4, nullptr, nullptr, nullptr,
                                             OF8P, (size_t)NB * 18 * NPIX, nullptr);
  reduceN_k<8><<<dim3((NB * 18 * NPIX / 4 + 255) / 256), blk, 0, stream>>>(
      OF8P, OFFS, NB * 18 * NPIX / 4);

  // deformable alignment + pw 1x1
  dgemm_k<<<dim3(NPIX / 128, NG, NB), blk, 0, stream>>>(CATF, OFFS, WD, dcn_b, FEAT);
  gemm1x1_k<C1, 0, true, 1><<<dim3(NPIX / 128, 1, NB), blk, 0, stream>>>(
      FEAT, WPW, pw_b, nullptr, AL);

  // kv path
  gemm1x1_k<C1, 0, false, 2><<<dim3(NPIX / 128, 2, NB), blk, 0, stream>>>(
      AL, WKV, nullptr, nullptr, KV1H);
  dw3x3h_k<<<dim3(NB * C2 * (NPIX / 8) / 256), blk, 0, stream>>>(KV1H, kvd_w, KVbH, C2);

  // attention
  gram_k<<<dim3(8, NHEADS, NB), blk, 0, stream>>>(QbH, KVbH, SACC, QSS, KSS);
  attnout_k<<<dim3(NPIX / 256, NHEADS, NB), blk, 0, stream>>>(SACC, QSS, KSS, temperature, KVbH, AO);
  gemm1x1_k<C1, 0, false, 0><<<dim3(NPIX / 128, 1, NB), blk, 0, stream>>>(
      AO, WPJ, nullptr, out, nullptr);
}

// Round 15
// 264.068 us; speedup vs baseline: 1.0458x; 1.0458x over previous
//
#include <hip/hip_runtime.h>
#include <math.h>

#define NB 2
#define C1 128
#define C2 256
#define HH 128
#define WW 128
#define NPIX (HH*WW)
#define NHEADS 8
#define DH 16
#define NG 8

typedef unsigned short u16;
typedef _Float16 f16;
typedef __attribute__((ext_vector_type(8))) _Float16 h8_t;
typedef __attribute__((ext_vector_type(4))) _Float16 h4_t;
typedef __attribute__((ext_vector_type(4))) float f4_t;

__device__ __forceinline__ float sigmoidf_(float v) { return 1.f / (1.f + expf(-v)); }

// ---- NCHW fp32 (y|x) -> NHWC f16 cat + fused 2x2 avgpool (f16 NHWC) ----
__global__ __launch_bounds__(256) void splitcat2_k(const float* __restrict__ y,
                                                   const float* __restrict__ x,
                                                   f16* __restrict__ catf,
                                                   f16* __restrict__ ph) {
  __shared__ float tile[256][33];
  int b = blockIdx.z, c0 = blockIdx.y * 32, rp = blockIdx.x;
  int tid = threadIdx.x;
  const float* src = (c0 < 128) ? y : x;
  int cc0 = c0 & 127;
  const int pbase = rp * 256;
  for (int e = tid; e < 8192; e += 256) {
    int c = e >> 8, p = e & 255;
    tile[p][c] = src[((size_t)b * C1 + cc0 + c) * NPIX + pbase + p];
  }
  __syncthreads();
  for (int e = tid; e < 8192; e += 256) {
    int p = e >> 5, c = e & 31;
    catf[((size_t)b * NPIX + pbase + p) * C2 + c0 + c] = (f16)tile[p][c];
  }
  for (int e = tid; e < 2048; e += 256) {
    int pp = e >> 5, c = e & 31;
    float v = 0.25f * (tile[2 * pp][c] + tile[2 * pp + 1][c] +
                       tile[128 + 2 * pp][c] + tile[128 + 2 * pp + 1][c]);
    ph[((size_t)b * 4096 + rp * 64 + pp) * C2 + c0 + c] = (f16)v;
  }
}

// ---------------- fused weight prep + accumulator zero (one launch) ----------------
__device__ __forceinline__ void wtrans_h(const float* __restrict__ w, f16* __restrict__ w2,
                                         int OC, int OCR, int idx) {
  int t = idx / (256 * OCR);
  int rem = idx - t * 256 * OCR;
  int ic = rem / OCR;
  int oc = rem - ic * OCR;
  float v = (oc < OC) ? w[((size_t)oc * 256 + ic) * 9 + t] : 0.f;
  w2[((size_t)(t * 8 + (ic >> 5)) * OCR + oc) * 32 + (ic & 31)] = (f16)v;
}

__global__ __launch_bounds__(256) void wprep_all_k(
    const float* __restrict__ q_w, const float* __restrict__ pw_w,
    const float* __restrict__ kv_w, const float* __restrict__ proj_w,
    const float* __restrict__ dcn_w, const float* __restrict__ k2_w,
    const float* __restrict__ k3_w, const float* __restrict__ k4_w,
    f16* __restrict__ WQ, f16* __restrict__ WPW, f16* __restrict__ WKV,
    f16* __restrict__ WPJ, f16* __restrict__ WD,
    f16* __restrict__ W2K2, f16* __restrict__ W2K3, f16* __restrict__ W2K4,
    float* __restrict__ sacc) {
  int idx = blockIdx.x * 256 + threadIdx.x;
  if (idx < 16384) { WQ[idx] = (f16)q_w[idx]; return; }
  idx -= 16384;
  if (idx < 16384) { WPW[idx] = (f16)pw_w[idx]; return; }
  idx -= 16384;
  if (idx < 32768) { WKV[idx] = (f16)kv_w[idx]; return; }
  idx -= 32768;
  if (idx < 16384) { WPJ[idx] = (f16)proj_w[idx]; return; }
  idx -= 16384;
  if (idx < 20480) {
    int oc = idx / 160, k = idx - oc * 160;
    int t = k >> 4, ic = k & 15;
    WD[idx] = (t < 9) ? (f16)dcn_w[((size_t)oc * 16 + ic) * 9 + t] : (f16)0.f;
    return;
  }
  idx -= 20480;
  if (idx < 589824) { wtrans_h(k2_w, W2K2, 256, 256, idx); return; }
  idx -= 589824;
  if (idx < 589824) { wtrans_h(k3_w, W2K3, 256, 256, idx); return; }
  idx -= 589824;
  if (idx < 73728) { wtrans_h(k4_w, W2K4, 18, 32, idx); return; }
  idx -= 73728;
  if (idx < 4608) sacc[idx] = 0.f;
}

// ---------------- implicit-GEMM 3x3 conv, fp16 MFMA, dbuf, split-K, PXB px tile ----------------
template<int PXB, int OCB, int NPAN, int SPLITK, int NGB, int WO, int HO, int WI, int HI, int PAD,
         int OCTOT, int OCR, bool GATE, bool OUTF_NHWC, bool SWZ>
__global__ __launch_bounds__(256) void convh_k(
    const f16* __restrict__ inA, const f16* __restrict__ w2,
    const float* __restrict__ gy, const float* __restrict__ gx,
    const float* __restrict__ gB,
    float* __restrict__ outFp, size_t pstride,
    f16* __restrict__ outC) {
  constexpr int CIN = 256;
  constexpr int MF = (PXB == 64) ? 2 : ((OCB == 128) ? 4 : 2);
  constexpr int NF = (OCB == 128) ? 4 : 2;
  constexpr int GCN = 72 / SPLITK;
  __shared__ f16 lds_a[2][PXB * 32];
  __shared__ f16 lds_w[2][OCB * 32];
  const int b = blockIdx.z;
  const int oc0 = (blockIdx.y % NPAN) * OCB;
  const int kz = blockIdx.y / NPAN;
  const int gbase = kz * GCN;
  float* outF = outFp + (size_t)kz * pstride;
  int bidx = blockIdx.x;
  if (SWZ) bidx = (bidx & 7) * ((int)gridDim.x >> 3) + (bidx >> 3);  // XCD-chunked (gridDim.x%8==0)
  const int px0 = bidx * PXB;
  const int tid = threadIdx.x;
  const int lane = tid & 63, wid = tid >> 6;
  const int wpx = (PXB == 64) ? ((wid & 1) * 32)
                              : ((OCB == 128) ? ((wid >> 1) * 64) : (wid * 32));
  const int woc = (PXB == 64) ? ((wid >> 1) * 64)
                              : ((OCB == 128) ? ((wid & 1) * 64) : 0);

  // A stager
  const int art = (PXB == 64) ? (tid >> 2) : (tid >> 1);
  const int aq = (PXB == 64) ? (tid & 3) : 0;      // PXB==64: one 16B slot
  const int shalf = (PXB == 64) ? 0 : (tid & 1);   // PXB==128: two 16B slots
  const int aopx = px0 + art;
  const int apy = aopx / WO, apxx = aopx % WO;
  const bool prow_ok = (aopx < HO * WO);
  int awo0, awo1;
  if (PXB == 64) {
    awo0 = art * 64 + ((aq ^ ((art >> 1) & 3)) << 4);
    awo1 = 0;
  } else {
    const int akey = (art >> 1) & 3;
    awo0 = art * 64 + (((shalf * 2 + 0) ^ akey) << 4);
    awo1 = art * 64 + (((shalf * 2 + 1) ^ akey) << 4);
  }
  // W stager
  const bool wact = (OCB == 128) ? true : (tid < OCB * 2);
  const int wrow = tid >> 1, whalf = tid & 1;
  const int wkey = (wrow >> 1) & 3;
  const int wwo0 = wrow * 64 + (((whalf * 2 + 0) ^ wkey) << 4);
  const int wwo1 = wrow * 64 + (((whalf * 2 + 1) ^ wkey) << 4);

  int aof[MF], wof[NF];
#pragma unroll
  for (int mf = 0; mf < MF; mf++) {
    int r = wpx + mf * 16 + (lane & 15);
    aof[mf] = r * 64 + (((lane >> 4) ^ ((r >> 1) & 3)) << 4);
  }
#pragma unroll
  for (int nf = 0; nf < NF; nf++) {
    int r = woc + nf * 16 + (lane & 15);
    wof[nf] = r * 64 + (((lane >> 4) ^ ((r >> 1) & 3)) << 4);
  }

  f4_t acc[MF][NF];
#pragma unroll
  for (int mf = 0; mf < MF; mf++)
#pragma unroll
    for (int nf = 0; nf < NF; nf++) { f4_t z = {0.f, 0.f, 0.f, 0.f}; acc[mf][nf] = z; }

  const size_t inb = (size_t)b * (HI * WI) * CIN;
  const size_t wg0 = (size_t)(oc0 + wrow) * 32 + (size_t)whalf * 16;
  uint4 ra0, ra1, rw0, rw1;

  auto load_gc = [&](int gc) {
    const int t = gc >> 3, c = gc & 7;
    const int iy = apy + (t / 3) - PAD;
    const int ix = apxx + (t % 3) - PAD;
    const bool val = prow_ok && iy >= 0 && iy < HI && ix >= 0 && ix < WI;
    uint4 z = {0, 0, 0, 0};
    ra0 = z; ra1 = z;
    if (val) {
      if (PXB == 64) {
        ra0 = *(const uint4*)(inA + inb + (size_t)(iy * WI + ix) * CIN + c * 32 + aq * 8);
      } else {
        const uint4* p = (const uint4*)(inA + inb + (size_t)(iy * WI + ix) * CIN + c * 32 + shalf * 16);
        ra0 = p[0];
        ra1 = p[1];
      }
    }
    if (wact) {
      const uint4* q = (const uint4*)(w2 + (size_t)gc * OCR * 32 + wg0);
      rw0 = q[0];
      rw1 = q[1];
    }
  };
  auto store_gc = [&](int nb) {
    char* la = (char*)lds_a[nb];
    char* lw = (char*)lds_w[nb];
    *(uint4*)(la + awo0) = ra0;
    if (PXB == 128) *(uint4*)(la + awo1) = ra1;
    if (wact) {
      *(uint4*)(lw + wwo0) = rw0;
      *(uint4*)(lw + wwo1) = rw1;
    }
  };

  load_gc(gbase);
  store_gc(0);
  __syncthreads();
  for (int i = 0; i < GCN; ++i) {
    const int cb = i & 1;
    if (i < GCN - 1) load_gc(gbase + i + 1);
    const char* la = (const char*)lds_a[cb];
    const char* lw = (const char*)lds_w[cb];
    h8_t af[MF], wf[NF];
#pragma unroll
    for (int mf = 0; mf < MF; mf++) af[mf] = *(const h8_t*)(la + aof[mf]);
#pragma unroll
    for (int nf = 0; nf < NF; nf++) wf[nf] = *(const h8_t*)(lw + wof[nf]);
#pragma unroll
    for (int mf = 0; mf < MF; mf++)
#pragma unroll
      for (int nf = 0; nf < NF; nf++)
        acc[mf][nf] = __builtin_amdgcn_mfma_f32_16x16x32_f16(af[mf], wf[nf], acc[mf][nf], 0, 0, 0);
    if (i < GCN - 1) store_gc(cb ^ 1);
    __syncthreads();
  }

  // epilogue: D row=(lane>>4)*4+r = px, col=lane&15 = oc  [m89-verified]
#pragma unroll
  for (int mf = 0; mf < MF; mf++) {
    const int pxb = px0 + wpx + mf * 16 + ((lane >> 4) << 2);
#pragma unroll
    for (int nf = 0; nf < NF; nf++) {
      const int oc = oc0 + woc + nf * 16 + (lane & 15);
      if (GATE) {
        const float* gp = (oc < 128) ? gy : gx;
        const size_t gbse = ((size_t)b * C1 + (oc & 127)) * NPIX;
        constexpr size_t gstride = (size_t)NB * 3844 * C2;
#pragma unroll
        for (int r = 0; r < 4; r++) {
          const int px = pxb + r;
          const int pyy = px >> 7, px2 = px & 127;
          const int iiy = (pyy * 62) >> 7, iix = (px2 * 62) >> 7;
          const size_t gi = ((size_t)b * 3844 + iiy * 62 + iix) * 256 + oc;
          float gv = gp[gbse + px];
#pragma unroll
          for (int pp = 0; pp < NGB; pp++) gv += gB[gi + (size_t)pp * gstride];
          float v = acc[mf][nf][r] * sigmoidf_(gv);
          outC[((size_t)b * NPIX + px) * C2 + oc] = (f16)v;
        }
      } else if (OUTF_NHWC) {
        if (oc < OCTOT) {
#pragma unroll
          for (int r = 0; r < 4; r++) {
            const int px = pxb + r;
            if (px < HO * WO)
              outF[((size_t)b * (HO * WO) + px) * OCTOT + oc] = acc[mf][nf][r];
          }
        }
      } else {
        if (pxb < HO * WO && oc < OCTOT)
          *(f4_t*)&outF[((size_t)b * OCTOT + oc) * (HO * WO) + pxb] = acc[mf][nf];
      }
    }
  }
}

// ---------------- sum NP split-K partial planes ----------------
template<int NP>
__global__ __launch_bounds__(256) void reduceN_k(const float* __restrict__ p,
                                                 float* __restrict__ o, int n4) {
  int i = blockIdx.x * 256 + threadIdx.x;
  if (i >= n4) return;
  const f4_t* v = (const f4_t*)p;
  f4_t r = v[i];
#pragma unroll
  for (int k = 1; k < NP; k++) {
    f4_t a = v[i + (size_t)k * n4];
    r[0] += a[0]; r[1] += a[1]; r[2] += a[2]; r[3] += a[3];
  }
  ((f4_t*)o)[i] = r;
}

// ---------------- 1x1 conv as fp16 MFMA GEMM, direct-global fragments ----------------
// OUTM: 0 = fp32 NCHW, 1 = f16 NHWC[128], 2 = f16 NCHW
template<int AS, int AOFF, bool BIAS, int OUTM>
__global__ __launch_bounds__(256) void gemm1x1_k(const f16* __restrict__ inA,
                                                 const f16* __restrict__ w,
                                                 const float* __restrict__ bias,
                                                 float* __restrict__ outF,
                                                 f16* __restrict__ outH) {
  const int b = blockIdx.z, nb0 = blockIdx.y * 128, px0 = blockIdx.x * 128;
  const int CoutTot = gridDim.y * 128;
  const int tid = threadIdx.x, lane = tid & 63, wid = tid >> 6;
  const int wpx = px0 + wid * 32;
  const int kslot = (lane >> 4) * 8;

  f4_t acc[2][8];
#pragma unroll
  for (int mf = 0; mf < 2; mf++)
#pragma unroll
    for (int nf = 0; nf < 8; nf++) { f4_t z = {0.f, 0.f, 0.f, 0.f}; acc[mf][nf] = z; }

  size_t arow[2];
#pragma unroll
  for (int mf = 0; mf < 2; mf++)
    arow[mf] = ((size_t)b * NPIX + wpx + mf * 16 + (lane & 15)) * AS + AOFF;
  size_t wrow[8];
#pragma unroll
  for (int nf = 0; nf < 8; nf++)
    wrow[nf] = (size_t)(nb0 + nf * 16 + (lane & 15)) * 128;

#pragma unroll
  for (int ks = 0; ks < 4; ks++) {
    const int ko = ks * 32 + kslot;
    h8_t a[2], bw[8];
#pragma unroll
    for (int mf = 0; mf < 2; mf++) a[mf] = *(const h8_t*)(inA + arow[mf] + ko);
#pragma unroll
    for (int nf = 0; nf < 8; nf++) bw[nf] = *(const h8_t*)(w + wrow[nf] + ko);
#pragma unroll
    for (int mf = 0; mf < 2; mf++)
#pragma unroll
      for (int nf = 0; nf < 8; nf++)
        acc[mf][nf] = __builtin_amdgcn_mfma_f32_16x16x32_f16(a[mf], bw[nf], acc[mf][nf], 0, 0, 0);
  }

#pragma unroll
  for (int mf = 0; mf < 2; mf++) {
    const int pxq = wpx + mf * 16 + (lane >> 4) * 4;
#pragma unroll
    for (int nf = 0; nf < 8; nf++) {
      const int oc = nb0 + nf * 16 + (lane & 15);
      f4_t v = acc[mf][nf];
      if (BIAS) {
        float bv = bias[oc];
        v[0] += bv; v[1] += bv; v[2] += bv; v[3] += bv;
      }
      if (OUTM == 1) {
#pragma unroll
        for (int r = 0; r < 4; r++)
          outH[((size_t)b * NPIX + pxq + r) * 128 + oc] = (f16)v[r];
      } else if (OUTM == 2) {
        h4_t o;
#pragma unroll
        for (int r = 0; r < 4; r++) o[r] = (f16)v[r];
        *(h4_t*)&outH[((size_t)b * CoutTot + oc) * NPIX + pxq] = o;
      } else {
        *(f4_t*)&outF[((size_t)b * CoutTot + oc) * NPIX + pxq] = v;
      }
    }
  }
}

// ---------------- fused modulated-deform-conv: NHWC f16 gather + grouped MFMA ----------------
__global__ __launch_bounds__(256) void dgemm_k(const f16* __restrict__ catf,
                                               const float* __restrict__ offs,
                                               const f16* __restrict__ wd,
                                               const float* __restrict__ dbias,
                                               f16* __restrict__ feat) {
  const int b = blockIdx.z, g = blockIdx.y;
  const int px0 = blockIdx.x * 128;
  const int tid = threadIdx.x;
  const int lane = tid & 63, wid = tid >> 6;
  const int chunk = lane >> 4;
  const int thalf = chunk >> 1;
  const int ic0 = (chunk & 1) * 8;
  const f16* yb = catf + (size_t)b * NPIX * C2;
  const float* ob = offs + (size_t)b * 18 * NPIX;

  int pm[2];
  float pyb[2], pxb2[2];
#pragma unroll
  for (int mf = 0; mf < 2; mf++) {
    pm[mf] = px0 + wid * 32 + mf * 16 + (lane & 15);
    pyb[mf] = (float)(pm[mf] >> 7);
    pxb2[mf] = (float)(pm[mf] & 127);
  }

  f4_t acc[2];
  { f4_t z = {0.f, 0.f, 0.f, 0.f}; acc[0] = z; acc[1] = z; }

  const size_t wbase = (size_t)(g * 16 + (lane & 15)) * 160;
#pragma unroll
  for (int s = 0; s < 5; s++) {
    h8_t ah[2];
#pragma unroll
    for (int mf = 0; mf < 2; mf++) {
      int t = 2 * s + thalf;
      int teff = t > 8 ? 8 : t;
      float dy = ob[(size_t)(2 * teff) * NPIX + pm[mf]];
      float dx = ob[(size_t)(2 * teff + 1) * NPIX + pm[mf]];
      float mk = sigmoidf_(ob[(size_t)teff * NPIX + pm[mf]]);
      int ky = teff / 3, kx = teff - 3 * ky;
      float pyf = pyb[mf] - 1.f + (float)ky + dy;
      float pxf = pxb2[mf] - 1.f + (float)kx + dx;
      float y0f = floorf(pyf), x0f = floorf(pxf);
      float fy = pyf - y0f, fx = pxf - x0f;
      int y0 = (int)y0f, x0 = (int)x0f;
      int y1 = y0 + 1, x1 = x0 + 1;
      float w00 = (1.f - fy) * (1.f - fx) * mk;
      float w01 = (1.f - fy) * fx * mk;
      float w10 = fy * (1.f - fx) * mk;
      float w11 = fy * fx * mk;
      bool vy0 = (y0 >= 0 && y0 < HH), vy1 = (y1 >= 0 && y1 < HH);
      bool vx0 = (x0 >= 0 && x0 < WW), vx1 = (x1 >= 0 && x1 < WW);
      if (!(vy0 && vx0)) w00 = 0.f;
      if (!(vy0 && vx1)) w01 = 0.f;
      if (!(vy1 && vx0)) w10 = 0.f;
      if (!(vy1 && vx1)) w11 = 0.f;
      int cy0 = min(max(y0, 0), HH - 1), cy1 = min(max(y1, 0), HH - 1);
      int cx0 = min(max(x0, 0), WW - 1), cx1 = min(max(x1, 0), WW - 1);
      const f16* p00 = yb + (size_t)(cy0 * WW + cx0) * C2 + g * 16 + ic0;
      const f16* p01 = yb + (size_t)(cy0 * WW + cx1) * C2 + g * 16 + ic0;
      const f16* p10 = yb + (size_t)(cy1 * WW + cx0) * C2 + g * 16 + ic0;
      const f16* p11 = yb + (size_t)(cy1 * WW + cx1) * C2 + g * 16 + ic0;
      h8_t a00 = *(const h8_t*)p00;
      h8_t a01 = *(const h8_t*)p01;
      h8_t a10 = *(const h8_t*)p10;
      h8_t a11 = *(const h8_t*)p11;
      h8_t hh;
#pragma unroll
      for (int j = 0; j < 8; j++) {
        float sv = w00 * (float)a00[j] + w01 * (float)a01[j] +
                   w10 * (float)a10[j] + w11 * (float)a11[j];
        hh[j] = (f16)sv;
      }
      ah[mf] = hh;
    }
    h8_t wv = *(const h8_t*)(wd + wbase + s * 32 + chunk * 8);
#pragma unroll
    for (int mf = 0; mf < 2; mf++)
      acc[mf] = __builtin_amdgcn_mfma_f32_16x16x32_f16(ah[mf], wv, acc[mf], 0, 0, 0);
  }

  const int oc = g * 16 + (lane & 15);
  const float bv = dbias[oc];
#pragma unroll
  for (int mf = 0; mf < 2; mf++) {
    const int pxq = px0 + wid * 32 + mf * 16 + (lane >> 4) * 4;
#pragma unroll
    for (int r = 0; r < 4; r++) {
      float v = fmaxf(acc[mf][r] + bv, 0.f);
      feat[((size_t)b * NPIX + pxq + r) * 128 + oc] = (f16)v;
    }
  }
}

// ---------------- depthwise 3x3, pad=1, f16 NCHW in/out, x8 vectorized ----------------
__global__ __launch_bounds__(256) void dw3x3h_k(const f16* __restrict__ in,
                                                const float* __restrict__ w,
                                                f16* __restrict__ out, int Cc) {
  int i8 = blockIdx.x * 256 + threadIdx.x;
  int total8 = NB * Cc * (NPIX / 8);
  if (i8 >= total8) return;
  int n8 = i8 & (NPIX / 8 - 1);
  int bc = i8 >> 11;
  int c = bc % Cc;
  int n = n8 << 3;
  int yy = n >> 7, xx = n & 127;
  const f16* p = in + (size_t)bc * NPIX;
  const float* wc = w + c * 9;
  float acc[8] = {0.f, 0.f, 0.f, 0.f, 0.f, 0.f, 0.f, 0.f};
#pragma unroll
  for (int ky = 0; ky < 3; ky++) {
    int iy = yy + ky - 1;
    if (iy < 0 || iy >= HH) continue;
    const f16* row = p + iy * WW;
    float v[10];
    v[0] = (xx > 0) ? (float)row[xx - 1] : 0.f;
    h8_t m = *(const h8_t*)(row + xx);
#pragma unroll
    for (int j = 0; j < 8; j++) v[j + 1] = (float)m[j];
    v[9] = (xx + 8 < WW) ? (float)row[xx + 8] : 0.f;
#pragma unroll
    for (int kx = 0; kx < 3; kx++) {
      float wv = wc[ky * 3 + kx];
#pragma unroll
      for (int j = 0; j < 8; j++) acc[j] += wv * v[j + kx];
    }
  }
  h8_t o;
#pragma unroll
  for (int j = 0; j < 8; j++) o[j] = (f16)acc[j];
  *(h8_t*)&out[(size_t)bc * NPIX + n] = o;
}

// ---------------- attention Gram (Q·K^T 16x16 over N=16384) via fp16 MFMA ----------------
__global__ __launch_bounds__(256) void gram_k(const f16* __restrict__ qbuf,
                                              const f16* __restrict__ kvbuf,
                                              float* __restrict__ s_acc,
                                              float* __restrict__ qss,
                                              float* __restrict__ kss) {
  int b = blockIdx.z, h = blockIdx.y;
  int tid = threadIdx.x, lane = tid & 63, wid = tid >> 6;
  int r = lane & 15, ks = lane >> 4;
  const f16* qb = qbuf + ((size_t)b * C1 + h * DH + r) * NPIX;
  const f16* kb = kvbuf + ((size_t)b * C2 + h * DH + r) * NPIX;
  int n0 = (blockIdx.x * 4 + wid) * 512;
  f4_t acc = {0.f, 0.f, 0.f, 0.f};
  float q2 = 0.f, k2 = 0.f;
  for (int s = 0; s < 16; s++) {
    int k = n0 + s * 32 + ks * 8;
    h8_t qv = *(const h8_t*)(qb + k);
    h8_t kv = *(const h8_t*)(kb + k);
#pragma unroll
    for (int j = 0; j < 8; j++) {
      float qf = (float)qv[j], kf = (float)kv[j];
      q2 += qf * qf;
      k2 += kf * kf;
    }
    acc = __builtin_amdgcn_mfma_f32_16x16x32_f16(qv, kv, acc, 0, 0, 0);
  }
  int bh = b * NHEADS + h;
#pragma unroll
  for (int rr = 0; rr < 4; rr++)
    atomicAdd(&s_acc[((size_t)bh * 16 + ks * 4 + rr) * 16 + r], acc[rr]);
  q2 += __shfl_xor(q2, 16);
  q2 += __shfl_xor(q2, 32);
  k2 += __shfl_xor(k2, 16);
  k2 += __shfl_xor(k2, 32);
  if (ks == 0) {
    atomicAdd(&qss[bh * 16 + r], q2);
    atomicAdd(&kss[bh * 16 + r], k2);
  }
}

// ---------------- attention: fused softmax + (attn @ v) -> NHWC f16 ----------------
__global__ __launch_bounds__(256) void attnout_k(const float* __restrict__ s_acc,
                                                 const float* __restrict__ qss,
                                                 const float* __restrict__ kss,
                                                 const float* __restrict__ temp,
                                                 const f16* __restrict__ kvbuf,
                                                 f16* __restrict__ outA) {
  __shared__ float S[16][17];
  __shared__ float A[16][17];
  __shared__ float qn[16], kn[16];
  int b = blockIdx.z, h = blockIdx.y;
  int tid = threadIdx.x;
  int bh = b * NHEADS + h;
  int dd = tid & 15, cc = tid >> 4;
  if (tid < 16) {
    qn[tid] = fmaxf(sqrtf(qss[bh * 16 + tid]), 1e-12f);
    kn[tid] = fmaxf(sqrtf(kss[bh * 16 + tid]), 1e-12f);
  }
  __syncthreads();
  float t = temp[h];
  float s = s_acc[((size_t)bh * 16 + cc) * 16 + dd] / (qn[cc] * kn[dd]) * t;
  S[cc][dd] = s;
  __syncthreads();
  float mx = -1e30f;
#pragma unroll
  for (int j = 0; j < 16; j++) mx = fmaxf(mx, S[cc][j]);
  float sum = 0.f;
#pragma unroll
  for (int j = 0; j < 16; j++) sum += expf(S[cc][j] - mx);
  A[cc][dd] = expf(s - mx) / sum;
  __syncthreads();

  int n = blockIdx.x * 256 + tid;
  const f16* vb = kvbuf + ((size_t)b * C2 + C1 + h * DH) * NPIX;
  float acc[16];
#pragma unroll
  for (int c = 0; c < 16; c++) acc[c] = 0.f;
#pragma unroll
  for (int d = 0; d < 16; d++) {
    float vv = (float)vb[(size_t)d * NPIX + n];
#pragma unroll
    for (int c = 0; c < 16; c++) acc[c] += A[c][d] * vv;
  }
  h8_t o0, o1;
#pragma unroll
  for (int c = 0; c < 8; c++) {
    o0[c] = (f16)acc[c];
    o1[c] = (f16)acc[8 + c];
  }
  size_t base = ((size_t)b * NPIX + n) * 128 + h * 16;
  *(h8_t*)(outA + base) = o0;
  *(h8_t*)(outA + base + 8) = o1;
}

extern "C" void kernel_launch(void* const* d_in, const int* in_sizes, int n_in,
                              void* d_out, int out_size, void* d_ws, size_t ws_size,
                              hipStream_t stream) {
  const float* x = (const float*)d_in[0];
  const float* y = (const float*)d_in[1];
  const float* q_w = (const float*)d_in[2];
  const float* qd_w = (const float*)d_in[3];
  const float* kv_w = (const float*)d_in[4];
  const float* kvd_w = (const float*)d_in[5];
  const float* proj_w = (const float*)d_in[6];
  const float* temperature = (const float*)d_in[7];
  const float* k2_w = (const float*)d_in[8];
  const float* k3_w = (const float*)d_in[9];
  const float* k4_w = (const float*)d_in[10];
  const float* dcn_w = (const float*)d_in[11];
  const float* dcn_b = (const float*)d_in[12];
  const float* pw_w = (const float*)d_in[13];
  const float* pw_b = (const float*)d_in[14];
  float* out = (float*)d_out;

  char* ws = (char*)d_ws;
  size_t off = 0;
  auto alloc = [&](size_t nbytes) {
    char* p = ws + off;
    off += (nbytes + 255) & ~(size_t)255;
    return p;
  };
  f16* CATF = (f16*)alloc((size_t)NB * NPIX * C2 * 2);
  f16* PH = (f16*)alloc((size_t)NB * 4096 * C2 * 2);
  float* A2 = (float*)alloc((size_t)4 * NB * 3844 * C2 * 4);
  f16* OUT3 = (f16*)alloc((size_t)NB * NPIX * C2 * 2);
  float* OF8P = (float*)alloc((size_t)8 * NB * 18 * NPIX * 4);
  float* OFFS = (float*)alloc((size_t)NB * 18 * NPIX * 4);
  f16* FEAT = (f16*)alloc((size_t)NB * NPIX * C1 * 2);
  f16* AL = (f16*)alloc((size_t)NB * NPIX * C1 * 2);
  f16* QbH = (f16*)alloc((size_t)NB * C1 * NPIX * 2);
  f16* W2K2 = (f16*)alloc((size_t)72 * 256 * 32 * 2);
  f16* W2K3 = (f16*)alloc((size_t)72 * 256 * 32 * 2);
  f16* W2K4 = (f16*)alloc((size_t)72 * 32 * 32 * 2);
  f16* WD = (f16*)alloc((size_t)128 * 160 * 2);
  f16* WQ = (f16*)alloc((size_t)128 * 128 * 2);
  f16* WPW = (f16*)alloc((size_t)128 * 128 * 2);
  f16* WKV = (f16*)alloc((size_t)256 * 128 * 2);
  f16* WPJ = (f16*)alloc((size_t)128 * 128 * 2);
  float* SACC = (float*)alloc((size_t)(NB * NHEADS * 256 + 512) * 4);
  float* QSS = SACC + NB * NHEADS * 256;
  float* KSS = QSS + 256;

  // region reuse (lifetimes)
  f16* QT1H = OUT3;             // q 1x1 out, f16 NCHW (dead before k3 writes OUT3)
  f16* KV1H = (f16*)A2;         // kv 1x1 out, f16 NCHW (A2 dead after k3's gate)
  f16* KVbH = OUT3;             // kv dw out, f16 NCHW (OUT3 dead after k4)
  f16* AO = FEAT;               // attn out (FEAT dead after pw)

  dim3 blk(256);

  wprep_all_k<<<dim3(5314), blk, 0, stream>>>(q_w, pw_w, kv_w, proj_w, dcn_w, k2_w, k3_w, k4_w,
                                              WQ, WPW, WKV, WPJ, WD, W2K2, W2K3, W2K4, SACC);

  splitcat2_k<<<dim3(64, C2 / 32, NB), blk, 0, stream>>>(y, x, CATF, PH);

  // q path
  gemm1x1_k<C2, C1, false, 2><<<dim3(NPIX / 128, 1, NB), blk, 0, stream>>>(
      CATF, WQ, nullptr, nullptr, QT1H);
  dw3x3h_k<<<dim3(NB * C1 * (NPIX / 8) / 256), blk, 0, stream>>>(QT1H, qd_w, QbH, C1);

  // offset head (fp16 single-product MFMA)
  convh_k<128, 128, 2, 4, 0, 62, 62, 64, 64, 0, 256, 256, false, true, false>
      <<<dim3(31, 8, NB), blk, 0, stream>>>(PH, W2K2, nullptr, nullptr, nullptr,
                                            A2, (size_t)NB * 3844 * C2, nullptr);
  // k3: 64-px tile (4 blocks/CU) + XCD swizzle
  convh_k<64, 128, 2, 1, 4, 128, 128, 128, 128, 1, 256, 256, true, false, true>
      <<<dim3(256, 2, NB), blk, 0, stream>>>(CATF, W2K3, y, x, A2, nullptr, 0, OUT3);
  convh_k<128, 32, 1, 8, 0, 128, 128, 128, 128, 1, 18, 32, false, false, true>
      <<<dim3(128, 8, NB), blk, 0, stream>>>(OUT3, W2K4, nullptr, nullptr, nullptr,
                                             OF8P, (size_t)NB * 18 * NPIX, nullptr);
  reduceN_k<8><<<dim3((NB * 18 * NPIX / 4 + 255) / 256), blk, 0, stream>>>(
      OF8P, OFFS, NB * 18 * NPIX / 4);

  // deformable alignment + pw 1x1
  dgemm_k<<<dim3(NPIX / 128, NG, NB), blk, 0, stream>>>(CATF, OFFS, WD, dcn_b, FEAT);
  gemm1x1_k<C1, 0, true, 1><<<dim3(NPIX / 128, 1, NB), blk, 0, stream>>>(
      FEAT, WPW, pw_b, nullptr, AL);

  // kv path
  gemm1x1_k<C1, 0, false, 2><<<dim3(NPIX / 128, 2, NB), blk, 0, stream>>>(
      AL, WKV, nullptr, nullptr, KV1H);
  dw3x3h_k<<<dim3(NB * C2 * (NPIX / 8) / 256), blk, 0, stream>>>(KV1H, kvd_w, KVbH, C2);

  // attention
  gram_k<<<dim3(8, NHEADS, NB), blk, 0, stream>>>(QbH, KVbH, SACC, QSS, KSS);
  attnout_k<<<dim3(NPIX / 256, NHEADS, NB), blk, 0, stream>>>(SACC, QSS, KSS, temperature, KVbH, AO);
  gemm1x1_k<C1, 0, false, 0><<<dim3(NPIX / 128, 1, NB), blk, 0, stream>>>(
      AO, WPJ, nullptr, out, nullptr);
}

// Round 16
// 263.565 us; speedup vs baseline: 1.0477x; 1.0019x over previous
//
#include <hip/hip_runtime.h>
#include <math.h>

#define NB 2
#define C1 128
#define C2 256
#define HH 128
#define WW 128
#define NPIX (HH*WW)
#define NHEADS 8
#define DH 16
#define NG 8

typedef unsigned short u16;
typedef _Float16 f16;
typedef __attribute__((ext_vector_type(8))) _Float16 h8_t;
typedef __attribute__((ext_vector_type(4))) _Float16 h4_t;
typedef __attribute__((ext_vector_type(4))) float f4_t;

__device__ __forceinline__ float sigmoidf_(float v) { return 1.f / (1.f + expf(-v)); }

// ---- NCHW fp32 (y|x) -> NHWC f16 cat + fused 2x2 avgpool (f16 NHWC) ----
__global__ __launch_bounds__(256) void splitcat2_k(const float* __restrict__ y,
                                                   const float* __restrict__ x,
                                                   f16* __restrict__ catf,
                                                   f16* __restrict__ ph) {
  __shared__ float tile[256][33];
  int b = blockIdx.z, c0 = blockIdx.y * 32, rp = blockIdx.x;
  int tid = threadIdx.x;
  const float* src = (c0 < 128) ? y : x;
  int cc0 = c0 & 127;
  const int pbase = rp * 256;
  for (int e = tid; e < 8192; e += 256) {
    int c = e >> 8, p = e & 255;
    tile[p][c] = src[((size_t)b * C1 + cc0 + c) * NPIX + pbase + p];
  }
  __syncthreads();
  for (int e = tid; e < 8192; e += 256) {
    int p = e >> 5, c = e & 31;
    catf[((size_t)b * NPIX + pbase + p) * C2 + c0 + c] = (f16)tile[p][c];
  }
  for (int e = tid; e < 2048; e += 256) {
    int pp = e >> 5, c = e & 31;
    float v = 0.25f * (tile[2 * pp][c] + tile[2 * pp + 1][c] +
                       tile[128 + 2 * pp][c] + tile[128 + 2 * pp + 1][c]);
    ph[((size_t)b * 4096 + rp * 64 + pp) * C2 + c0 + c] = (f16)v;
  }
}

// ---------------- fused weight prep + accumulator zero (one launch) ----------------
__device__ __forceinline__ void wtrans_h(const float* __restrict__ w, f16* __restrict__ w2,
                                         int OC, int OCR, int idx) {
  int t = idx / (256 * OCR);
  int rem = idx - t * 256 * OCR;
  int ic = rem / OCR;
  int oc = rem - ic * OCR;
  float v = (oc < OC) ? w[((size_t)oc * 256 + ic) * 9 + t] : 0.f;
  w2[((size_t)(t * 8 + (ic >> 5)) * OCR + oc) * 32 + (ic & 31)] = (f16)v;
}

__global__ __launch_bounds__(256) void wprep_all_k(
    const float* __restrict__ q_w, const float* __restrict__ pw_w,
    const float* __restrict__ kv_w, const float* __restrict__ proj_w,
    const float* __restrict__ dcn_w, const float* __restrict__ k2_w,
    const float* __restrict__ k3_w, const float* __restrict__ k4_w,
    f16* __restrict__ WQ, f16* __restrict__ WPW, f16* __restrict__ WKV,
    f16* __restrict__ WPJ, f16* __restrict__ WD,
    f16* __restrict__ W2K2, f16* __restrict__ W2K3, f16* __restrict__ W2K4,
    float* __restrict__ sacc) {
  int idx = blockIdx.x * 256 + threadIdx.x;
  if (idx < 16384) { WQ[idx] = (f16)q_w[idx]; return; }
  idx -= 16384;
  if (idx < 16384) { WPW[idx] = (f16)pw_w[idx]; return; }
  idx -= 16384;
  if (idx < 32768) { WKV[idx] = (f16)kv_w[idx]; return; }
  idx -= 32768;
  if (idx < 16384) { WPJ[idx] = (f16)proj_w[idx]; return; }
  idx -= 16384;
  if (idx < 20480) {
    int oc = idx / 160, k = idx - oc * 160;
    int t = k >> 4, ic = k & 15;
    WD[idx] = (t < 9) ? (f16)dcn_w[((size_t)oc * 16 + ic) * 9 + t] : (f16)0.f;
    return;
  }
  idx -= 20480;
  if (idx < 589824) { wtrans_h(k2_w, W2K2, 256, 256, idx); return; }
  idx -= 589824;
  if (idx < 589824) { wtrans_h(k3_w, W2K3, 256, 256, idx); return; }
  idx -= 589824;
  if (idx < 73728) { wtrans_h(k4_w, W2K4, 18, 32, idx); return; }
  idx -= 73728;
  if (idx < 4608) sacc[idx] = 0.f;
}

// ---------------- implicit-GEMM 3x3 conv, fp16 MFMA, dbuf, split-K, PXB px tile ----------------
template<int PXB, int OCB, int NPAN, int SPLITK, int NGB, int WO, int HO, int WI, int HI, int PAD,
         int OCTOT, int OCR, bool GATE, bool OUTF_NHWC, bool SWZ>
__global__ __launch_bounds__(256) void convh_k(
    const f16* __restrict__ inA, const f16* __restrict__ w2,
    const float* __restrict__ gy, const float* __restrict__ gx,
    const float* __restrict__ gB,
    float* __restrict__ outFp, size_t pstride,
    f16* __restrict__ outC) {
  constexpr int CIN = 256;
  constexpr int MF = (PXB == 64) ? 2 : ((OCB == 128) ? 4 : 2);
  constexpr int NF = (OCB == 128) ? 4 : 2;
  constexpr int GCN = 72 / SPLITK;
  __shared__ f16 lds_a[2][PXB * 32];
  __shared__ f16 lds_w[2][OCB * 32];
  const int b = blockIdx.z;
  const int oc0 = (blockIdx.y % NPAN) * OCB;
  const int kz = blockIdx.y / NPAN;
  const int gbase = kz * GCN;
  float* outF = outFp + (size_t)kz * pstride;
  int bidx = blockIdx.x;
  if (SWZ) bidx = (bidx & 7) * ((int)gridDim.x >> 3) + (bidx >> 3);  // XCD-chunked (gridDim.x%8==0)
  const int px0 = bidx * PXB;
  const int tid = threadIdx.x;
  const int lane = tid & 63, wid = tid >> 6;
  const int wpx = (PXB == 64) ? ((wid & 1) * 32)
                              : ((OCB == 128) ? ((wid >> 1) * 64) : (wid * 32));
  const int woc = (PXB == 64) ? ((wid >> 1) * 64)
                              : ((OCB == 128) ? ((wid & 1) * 64) : 0);

  // A stager
  const int art = (PXB == 64) ? (tid >> 2) : (tid >> 1);
  const int aq = (PXB == 64) ? (tid & 3) : 0;      // PXB==64: one 16B slot
  const int shalf = (PXB == 64) ? 0 : (tid & 1);   // PXB==128: two 16B slots
  const int aopx = px0 + art;
  const int apy = aopx / WO, apxx = aopx % WO;
  const bool prow_ok = (aopx < HO * WO);
  int awo0, awo1;
  if (PXB == 64) {
    awo0 = art * 64 + ((aq ^ ((art >> 1) & 3)) << 4);
    awo1 = 0;
  } else {
    const int akey = (art >> 1) & 3;
    awo0 = art * 64 + (((shalf * 2 + 0) ^ akey) << 4);
    awo1 = art * 64 + (((shalf * 2 + 1) ^ akey) << 4);
  }
  // W stager
  const bool wact = (OCB == 128) ? true : (tid < OCB * 2);
  const int wrow = tid >> 1, whalf = tid & 1;
  const int wkey = (wrow >> 1) & 3;
  const int wwo0 = wrow * 64 + (((whalf * 2 + 0) ^ wkey) << 4);
  const int wwo1 = wrow * 64 + (((whalf * 2 + 1) ^ wkey) << 4);

  int aof[MF], wof[NF];
#pragma unroll
  for (int mf = 0; mf < MF; mf++) {
    int r = wpx + mf * 16 + (lane & 15);
    aof[mf] = r * 64 + (((lane >> 4) ^ ((r >> 1) & 3)) << 4);
  }
#pragma unroll
  for (int nf = 0; nf < NF; nf++) {
    int r = woc + nf * 16 + (lane & 15);
    wof[nf] = r * 64 + (((lane >> 4) ^ ((r >> 1) & 3)) << 4);
  }

  f4_t acc[MF][NF];
#pragma unroll
  for (int mf = 0; mf < MF; mf++)
#pragma unroll
    for (int nf = 0; nf < NF; nf++) { f4_t z = {0.f, 0.f, 0.f, 0.f}; acc[mf][nf] = z; }

  const size_t inb = (size_t)b * (HI * WI) * CIN;
  const size_t wg0 = (size_t)(oc0 + wrow) * 32 + (size_t)whalf * 16;
  uint4 ra0, ra1, rw0, rw1;

  auto load_gc = [&](int gc) {
    const int t = gc >> 3, c = gc & 7;
    const int iy = apy + (t / 3) - PAD;
    const int ix = apxx + (t % 3) - PAD;
    const bool val = prow_ok && iy >= 0 && iy < HI && ix >= 0 && ix < WI;
    uint4 z = {0, 0, 0, 0};
    ra0 = z; ra1 = z;
    if (val) {
      if (PXB == 64) {
        ra0 = *(const uint4*)(inA + inb + (size_t)(iy * WI + ix) * CIN + c * 32 + aq * 8);
      } else {
        const uint4* p = (const uint4*)(inA + inb + (size_t)(iy * WI + ix) * CIN + c * 32 + shalf * 16);
        ra0 = p[0];
        ra1 = p[1];
      }
    }
    if (wact) {
      const uint4* q = (const uint4*)(w2 + (size_t)gc * OCR * 32 + wg0);
      rw0 = q[0];
      rw1 = q[1];
    }
  };
  auto store_gc = [&](int nb) {
    char* la = (char*)lds_a[nb];
    char* lw = (char*)lds_w[nb];
    *(uint4*)(la + awo0) = ra0;
    if (PXB == 128) *(uint4*)(la + awo1) = ra1;
    if (wact) {
      *(uint4*)(lw + wwo0) = rw0;
      *(uint4*)(lw + wwo1) = rw1;
    }
  };

  load_gc(gbase);
  store_gc(0);
  __syncthreads();
  for (int i = 0; i < GCN; ++i) {
    const int cb = i & 1;
    if (i < GCN - 1) load_gc(gbase + i + 1);
    const char* la = (const char*)lds_a[cb];
    const char* lw = (const char*)lds_w[cb];
    h8_t af[MF], wf[NF];
#pragma unroll
    for (int mf = 0; mf < MF; mf++) af[mf] = *(const h8_t*)(la + aof[mf]);
#pragma unroll
    for (int nf = 0; nf < NF; nf++) wf[nf] = *(const h8_t*)(lw + wof[nf]);
#pragma unroll
    for (int mf = 0; mf < MF; mf++)
#pragma unroll
      for (int nf = 0; nf < NF; nf++)
        acc[mf][nf] = __builtin_amdgcn_mfma_f32_16x16x32_f16(af[mf], wf[nf], acc[mf][nf], 0, 0, 0);
    if (i < GCN - 1) store_gc(cb ^ 1);
    __syncthreads();
  }

  // epilogue: D row=(lane>>4)*4+r = px, col=lane&15 = oc  [m89-verified]
#pragma unroll
  for (int mf = 0; mf < MF; mf++) {
    const int pxb = px0 + wpx + mf * 16 + ((lane >> 4) << 2);
#pragma unroll
    for (int nf = 0; nf < NF; nf++) {
      const int oc = oc0 + woc + nf * 16 + (lane & 15);
      if (GATE) {
        const float* gp = (oc < 128) ? gy : gx;
        const size_t gbse = ((size_t)b * C1 + (oc & 127)) * NPIX;
        constexpr size_t gstride = (size_t)NB * 3844 * C2;
#pragma unroll
        for (int r = 0; r < 4; r++) {
          const int px = pxb + r;
          const int pyy = px >> 7, px2 = px & 127;
          const int iiy = (pyy * 62) >> 7, iix = (px2 * 62) >> 7;
          const size_t gi = ((size_t)b * 3844 + iiy * 62 + iix) * 256 + oc;
          float gv = gp[gbse + px];
#pragma unroll
          for (int pp = 0; pp < NGB; pp++) gv += gB[gi + (size_t)pp * gstride];
          float v = acc[mf][nf][r] * sigmoidf_(gv);
          outC[((size_t)b * NPIX + px) * C2 + oc] = (f16)v;
        }
      } else if (OUTF_NHWC) {
        if (oc < OCTOT) {
#pragma unroll
          for (int r = 0; r < 4; r++) {
            const int px = pxb + r;
            if (px < HO * WO)
              outF[((size_t)b * (HO * WO) + px) * OCTOT + oc] = acc[mf][nf][r];
          }
        }
      } else {
        if (pxb < HO * WO && oc < OCTOT)
          *(f4_t*)&outF[((size_t)b * OCTOT + oc) * (HO * WO) + pxb] = acc[mf][nf];
      }
    }
  }
}

// ---------------- sum NP split-K partial planes ----------------
template<int NP>
__global__ __launch_bounds__(256) void reduceN_k(const float* __restrict__ p,
                                                 float* __restrict__ o, int n4) {
  int i = blockIdx.x * 256 + threadIdx.x;
  if (i >= n4) return;
  const f4_t* v = (const f4_t*)p;
  f4_t r = v[i];
#pragma unroll
  for (int k = 1; k < NP; k++) {
    f4_t a = v[i + (size_t)k * n4];
    r[0] += a[0]; r[1] += a[1]; r[2] += a[2]; r[3] += a[3];
  }
  ((f4_t*)o)[i] = r;
}

// ---------------- 1x1 conv as fp16 MFMA GEMM, direct-global fragments ----------------
// OUTM: 0 = fp32 NCHW, 1 = f16 NHWC[128], 2 = f16 NCHW
template<int AS, int AOFF, bool BIAS, int OUTM>
__global__ __launch_bounds__(256) void gemm1x1_k(const f16* __restrict__ inA,
                                                 const f16* __restrict__ w,
                                                 const float* __restrict__ bias,
                                                 float* __restrict__ outF,
                                                 f16* __restrict__ outH) {
  const int b = blockIdx.z, nb0 = blockIdx.y * 128, px0 = blockIdx.x * 128;
  const int CoutTot = gridDim.y * 128;
  const int tid = threadIdx.x, lane = tid & 63, wid = tid >> 6;
  const int wpx = px0 + wid * 32;
  const int kslot = (lane >> 4) * 8;

  f4_t acc[2][8];
#pragma unroll
  for (int mf = 0; mf < 2; mf++)
#pragma unroll
    for (int nf = 0; nf < 8; nf++) { f4_t z = {0.f, 0.f, 0.f, 0.f}; acc[mf][nf] = z; }

  size_t arow[2];
#pragma unroll
  for (int mf = 0; mf < 2; mf++)
    arow[mf] = ((size_t)b * NPIX + wpx + mf * 16 + (lane & 15)) * AS + AOFF;
  size_t wrow[8];
#pragma unroll
  for (int nf = 0; nf < 8; nf++)
    wrow[nf] = (size_t)(nb0 + nf * 16 + (lane & 15)) * 128;

#pragma unroll
  for (int ks = 0; ks < 4; ks++) {
    const int ko = ks * 32 + kslot;
    h8_t a[2], bw[8];
#pragma unroll
    for (int mf = 0; mf < 2; mf++) a[mf] = *(const h8_t*)(inA + arow[mf] + ko);
#pragma unroll
    for (int nf = 0; nf < 8; nf++) bw[nf] = *(const h8_t*)(w + wrow[nf] + ko);
#pragma unroll
    for (int mf = 0; mf < 2; mf++)
#pragma unroll
      for (int nf = 0; nf < 8; nf++)
        acc[mf][nf] = __builtin_amdgcn_mfma_f32_16x16x32_f16(a[mf], bw[nf], acc[mf][nf], 0, 0, 0);
  }

#pragma unroll
  for (int mf = 0; mf < 2; mf++) {
    const int pxq = wpx + mf * 16 + (lane >> 4) * 4;
#pragma unroll
    for (int nf = 0; nf < 8; nf++) {
      const int oc = nb0 + nf * 16 + (lane & 15);
      f4_t v = acc[mf][nf];
      if (BIAS) {
        float bv = bias[oc];
        v[0] += bv; v[1] += bv; v[2] += bv; v[3] += bv;
      }
      if (OUTM == 1) {
#pragma unroll
        for (int r = 0; r < 4; r++)
          outH[((size_t)b * NPIX + pxq + r) * 128 + oc] = (f16)v[r];
      } else if (OUTM == 2) {
        h4_t o;
#pragma unroll
        for (int r = 0; r < 4; r++) o[r] = (f16)v[r];
        *(h4_t*)&outH[((size_t)b * CoutTot + oc) * NPIX + pxq] = o;
      } else {
        *(f4_t*)&outF[((size_t)b * CoutTot + oc) * NPIX + pxq] = v;
      }
    }
  }
}

// ---------------- fused modulated-deform-conv: NHWC f16 gather + grouped MFMA ----------------
__global__ __launch_bounds__(256) void dgemm_k(const f16* __restrict__ catf,
                                               const float* __restrict__ offs,
                                               const f16* __restrict__ wd,
                                               const float* __restrict__ dbias,
                                               f16* __restrict__ feat) {
  const int b = blockIdx.z, g = blockIdx.y;
  const int px0 = blockIdx.x * 128;
  const int tid = threadIdx.x;
  const int lane = tid & 63, wid = tid >> 6;
  const int chunk = lane >> 4;
  const int thalf = chunk >> 1;
  const int ic0 = (chunk & 1) * 8;
  const f16* yb = catf + (size_t)b * NPIX * C2;
  const float* ob = offs + (size_t)b * 18 * NPIX;

  int pm[2];
  float pyb[2], pxb2[2];
#pragma unroll
  for (int mf = 0; mf < 2; mf++) {
    pm[mf] = px0 + wid * 32 + mf * 16 + (lane & 15);
    pyb[mf] = (float)(pm[mf] >> 7);
    pxb2[mf] = (float)(pm[mf] & 127);
  }

  f4_t acc[2];
  { f4_t z = {0.f, 0.f, 0.f, 0.f}; acc[0] = z; acc[1] = z; }

  const size_t wbase = (size_t)(g * 16 + (lane & 15)) * 160;
#pragma unroll
  for (int s = 0; s < 5; s++) {
    h8_t ah[2];
#pragma unroll
    for (int mf = 0; mf < 2; mf++) {
      int t = 2 * s + thalf;
      int teff = t > 8 ? 8 : t;
      float dy = ob[(size_t)(2 * teff) * NPIX + pm[mf]];
      float dx = ob[(size_t)(2 * teff + 1) * NPIX + pm[mf]];
      float mk = sigmoidf_(ob[(size_t)teff * NPIX + pm[mf]]);
      int ky = teff / 3, kx = teff - 3 * ky;
      float pyf = pyb[mf] - 1.f + (float)ky + dy;
      float pxf = pxb2[mf] - 1.f + (float)kx + dx;
      float y0f = floorf(pyf), x0f = floorf(pxf);
      float fy = pyf - y0f, fx = pxf - x0f;
      int y0 = (int)y0f, x0 = (int)x0f;
      int y1 = y0 + 1, x1 = x0 + 1;
      float w00 = (1.f - fy) * (1.f - fx) * mk;
      float w01 = (1.f - fy) * fx * mk;
      float w10 = fy * (1.f - fx) * mk;
      float w11 = fy * fx * mk;
      bool vy0 = (y0 >= 0 && y0 < HH), vy1 = (y1 >= 0 && y1 < HH);
      bool vx0 = (x0 >= 0 && x0 < WW), vx1 = (x1 >= 0 && x1 < WW);
      if (!(vy0 && vx0)) w00 = 0.f;
      if (!(vy0 && vx1)) w01 = 0.f;
      if (!(vy1 && vx0)) w10 = 0.f;
      if (!(vy1 && vx1)) w11 = 0.f;
      int cy0 = min(max(y0, 0), HH - 1), cy1 = min(max(y1, 0), HH - 1);
      int cx0 = min(max(x0, 0), WW - 1), cx1 = min(max(x1, 0), WW - 1);
      const f16* p00 = yb + (size_t)(cy0 * WW + cx0) * C2 + g * 16 + ic0;
      const f16* p01 = yb + (size_t)(cy0 * WW + cx1) * C2 + g * 16 + ic0;
      const f16* p10 = yb + (size_t)(cy1 * WW + cx0) * C2 + g * 16 + ic0;
      const f16* p11 = yb + (size_t)(cy1 * WW + cx1) * C2 + g * 16 + ic0;
      h8_t a00 = *(const h8_t*)p00;
      h8_t a01 = *(const h8_t*)p01;
      h8_t a10 = *(const h8_t*)p10;
      h8_t a11 = *(const h8_t*)p11;
      h8_t hh;
#pragma unroll
      for (int j = 0; j < 8; j++) {
        float sv = w00 * (float)a00[j] + w01 * (float)a01[j] +
                   w10 * (float)a10[j] + w11 * (float)a11[j];
        hh[j] = (f16)sv;
      }
      ah[mf] = hh;
    }
    h8_t wv = *(const h8_t*)(wd + wbase + s * 32 + chunk * 8);
#pragma unroll
    for (int mf = 0; mf < 2; mf++)
      acc[mf] = __builtin_amdgcn_mfma_f32_16x16x32_f16(ah[mf], wv, acc[mf], 0, 0, 0);
  }

  const int oc = g * 16 + (lane & 15);
  const float bv = dbias[oc];
#pragma unroll
  for (int mf = 0; mf < 2; mf++) {
    const int pxq = px0 + wid * 32 + mf * 16 + (lane >> 4) * 4;
#pragma unroll
    for (int r = 0; r < 4; r++) {
      float v = fmaxf(acc[mf][r] + bv, 0.f);
      feat[((size_t)b * NPIX + pxq + r) * 128 + oc] = (f16)v;
    }
  }
}

// ---------------- depthwise 3x3, pad=1, f16 NCHW in/out, x8 vectorized ----------------
__global__ __launch_bounds__(256) void dw3x3h_k(const f16* __restrict__ in,
                                                const float* __restrict__ w,
                                                f16* __restrict__ out, int Cc) {
  int i8 = blockIdx.x * 256 + threadIdx.x;
  int total8 = NB * Cc * (NPIX / 8);
  if (i8 >= total8) return;
  int n8 = i8 & (NPIX / 8 - 1);
  int bc = i8 >> 11;
  int c = bc % Cc;
  int n = n8 << 3;
  int yy = n >> 7, xx = n & 127;
  const f16* p = in + (size_t)bc * NPIX;
  const float* wc = w + c * 9;
  float acc[8] = {0.f, 0.f, 0.f, 0.f, 0.f, 0.f, 0.f, 0.f};
#pragma unroll
  for (int ky = 0; ky < 3; ky++) {
    int iy = yy + ky - 1;
    if (iy < 0 || iy >= HH) continue;
    const f16* row = p + iy * WW;
    float v[10];
    v[0] = (xx > 0) ? (float)row[xx - 1] : 0.f;
    h8_t m = *(const h8_t*)(row + xx);
#pragma unroll
    for (int j = 0; j < 8; j++) v[j + 1] = (float)m[j];
    v[9] = (xx + 8 < WW) ? (float)row[xx + 8] : 0.f;
#pragma unroll
    for (int kx = 0; kx < 3; kx++) {
      float wv = wc[ky * 3 + kx];
#pragma unroll
      for (int j = 0; j < 8; j++) acc[j] += wv * v[j + kx];
    }
  }
  h8_t o;
#pragma unroll
  for (int j = 0; j < 8; j++) o[j] = (f16)acc[j];
  *(h8_t*)&out[(size_t)bc * NPIX + n] = o;
}

// ---------------- attention Gram (Q·K^T 16x16 over N=16384) via fp16 MFMA ----------------
__global__ __launch_bounds__(256) void gram_k(const f16* __restrict__ qbuf,
                                              const f16* __restrict__ kvbuf,
                                              float* __restrict__ s_acc,
                                              float* __restrict__ qss,
                                              float* __restrict__ kss) {
  int b = blockIdx.z, h = blockIdx.y;
  int tid = threadIdx.x, lane = tid & 63, wid = tid >> 6;
  int r = lane & 15, ks = lane >> 4;
  const f16* qb = qbuf + ((size_t)b * C1 + h * DH + r) * NPIX;
  const f16* kb = kvbuf + ((size_t)b * C2 + h * DH + r) * NPIX;
  int n0 = (blockIdx.x * 4 + wid) * 512;
  f4_t acc = {0.f, 0.f, 0.f, 0.f};
  float q2 = 0.f, k2 = 0.f;
  for (int s = 0; s < 16; s++) {
    int k = n0 + s * 32 + ks * 8;
    h8_t qv = *(const h8_t*)(qb + k);
    h8_t kv = *(const h8_t*)(kb + k);
#pragma unroll
    for (int j = 0; j < 8; j++) {
      float qf = (float)qv[j], kf = (float)kv[j];
      q2 += qf * qf;
      k2 += kf * kf;
    }
    acc = __builtin_amdgcn_mfma_f32_16x16x32_f16(qv, kv, acc, 0, 0, 0);
  }
  int bh = b * NHEADS + h;
#pragma unroll
  for (int rr = 0; rr < 4; rr++)
    atomicAdd(&s_acc[((size_t)bh * 16 + ks * 4 + rr) * 16 + r], acc[rr]);
  q2 += __shfl_xor(q2, 16);
  q2 += __shfl_xor(q2, 32);
  k2 += __shfl_xor(k2, 16);
  k2 += __shfl_xor(k2, 32);
  if (ks == 0) {
    atomicAdd(&qss[bh * 16 + r], q2);
    atomicAdd(&kss[bh * 16 + r], k2);
  }
}

// ---------------- attention: fused softmax + (attn @ v) -> NHWC f16 ----------------
__global__ __launch_bounds__(256) void attnout_k(const float* __restrict__ s_acc,
                                                 const float* __restrict__ qss,
                                                 const float* __restrict__ kss,
                                                 const float* __restrict__ temp,
                                                 const f16* __restrict__ kvbuf,
                                                 f16* __restrict__ outA) {
  __shared__ float S[16][17];
  __shared__ float A[16][17];
  __shared__ float qn[16], kn[16];
  int b = blockIdx.z, h = blockIdx.y;
  int tid = threadIdx.x;
  int bh = b * NHEADS + h;
  int dd = tid & 15, cc = tid >> 4;
  if (tid < 16) {
    qn[tid] = fmaxf(sqrtf(qss[bh * 16 + tid]), 1e-12f);
    kn[tid] = fmaxf(sqrtf(kss[bh * 16 + tid]), 1e-12f);
  }
  __syncthreads();
  float t = temp[h];
  float s = s_acc[((size_t)bh * 16 + cc) * 16 + dd] / (qn[cc] * kn[dd]) * t;
  S[cc][dd] = s;
  __syncthreads();
  float mx = -1e30f;
#pragma unroll
  for (int j = 0; j < 16; j++) mx = fmaxf(mx, S[cc][j]);
  float sum = 0.f;
#pragma unroll
  for (int j = 0; j < 16; j++) sum += expf(S[cc][j] - mx);
  A[cc][dd] = expf(s - mx) / sum;
  __syncthreads();

  int n = blockIdx.x * 256 + tid;
  const f16* vb = kvbuf + ((size_t)b * C2 + C1 + h * DH) * NPIX;
  float acc[16];
#pragma unroll
  for (int c = 0; c < 16; c++) acc[c] = 0.f;
#pragma unroll
  for (int d = 0; d < 16; d++) {
    float vv = (float)vb[(size_t)d * NPIX + n];
#pragma unroll
    for (int c = 0; c < 16; c++) acc[c] += A[c][d] * vv;
  }
  h8_t o0, o1;
#pragma unroll
  for (int c = 0; c < 8; c++) {
    o0[c] = (f16)acc[c];
    o1[c] = (f16)acc[8 + c];
  }
  size_t base = ((size_t)b * NPIX + n) * 128 + h * 16;
  *(h8_t*)(outA + base) = o0;
  *(h8_t*)(outA + base + 8) = o1;
}

extern "C" void kernel_launch(void* const* d_in, const int* in_sizes, int n_in,
                              void* d_out, int out_size, void* d_ws, size_t ws_size,
                              hipStream_t stream) {
  const float* x = (const float*)d_in[0];
  const float* y = (const float*)d_in[1];
  const float* q_w = (const float*)d_in[2];
  const float* qd_w = (const float*)d_in[3];
  const float* kv_w = (const float*)d_in[4];
  const float* kvd_w = (const float*)d_in[5];
  const float* proj_w = (const float*)d_in[6];
  const float* temperature = (const float*)d_in[7];
  const float* k2_w = (const float*)d_in[8];
  const float* k3_w = (const float*)d_in[9];
  const float* k4_w = (const float*)d_in[10];
  const float* dcn_w = (const float*)d_in[11];
  const float* dcn_b = (const float*)d_in[12];
  const float* pw_w = (const float*)d_in[13];
  const float* pw_b = (const float*)d_in[14];
  float* out = (float*)d_out;

  char* ws = (char*)d_ws;
  size_t off = 0;
  auto alloc = [&](size_t nbytes) {
    char* p = ws + off;
    off += (nbytes + 255) & ~(size_t)255;
    return p;
  };
  f16* CATF = (f16*)alloc((size_t)NB * NPIX * C2 * 2);
  f16* PH = (f16*)alloc((size_t)NB * 4096 * C2 * 2);
  float* A2 = (float*)alloc((size_t)4 * NB * 3844 * C2 * 4);
  f16* OUT3 = (f16*)alloc((size_t)NB * NPIX * C2 * 2);
  float* OF8P = (float*)alloc((size_t)8 * NB * 18 * NPIX * 4);
  float* OFFS = (float*)alloc((size_t)NB * 18 * NPIX * 4);
  f16* FEAT = (f16*)alloc((size_t)NB * NPIX * C1 * 2);
  f16* AL = (f16*)alloc((size_t)NB * NPIX * C1 * 2);
  f16* QbH = (f16*)alloc((size_t)NB * C1 * NPIX * 2);
  f16* W2K2 = (f16*)alloc((size_t)72 * 256 * 32 * 2);
  f16* W2K3 = (f16*)alloc((size_t)72 * 256 * 32 * 2);
  f16* W2K4 = (f16*)alloc((size_t)72 * 32 * 32 * 2);
  f16* WD = (f16*)alloc((size_t)128 * 160 * 2);
  f16* WQ = (f16*)alloc((size_t)128 * 128 * 2);
  f16* WPW = (f16*)alloc((size_t)128 * 128 * 2);
  f16* WKV = (f16*)alloc((size_t)256 * 128 * 2);
  f16* WPJ = (f16*)alloc((size_t)128 * 128 * 2);
  float* SACC = (float*)alloc((size_t)(NB * NHEADS * 256 + 512) * 4);
  float* QSS = SACC + NB * NHEADS * 256;
  float* KSS = QSS + 256;

  // region reuse (lifetimes)
  f16* QT1H = OUT3;             // q 1x1 out, f16 NCHW (dead before k3 writes OUT3)
  f16* KV1H = (f16*)A2;         // kv 1x1 out, f16 NCHW (A2 dead after k3's gate)
  f16* KVbH = OUT3;             // kv dw out, f16 NCHW (OUT3 dead after k4)
  f16* AO = FEAT;               // attn out (FEAT dead after pw)

  dim3 blk(256);

  wprep_all_k<<<dim3(5314), blk, 0, stream>>>(q_w, pw_w, kv_w, proj_w, dcn_w, k2_w, k3_w, k4_w,
                                              WQ, WPW, WKV, WPJ, WD, W2K2, W2K3, W2K4, SACC);

  splitcat2_k<<<dim3(64, C2 / 32, NB), blk, 0, stream>>>(y, x, CATF, PH);

  // q path
  gemm1x1_k<C2, C1, false, 2><<<dim3(NPIX / 128, 1, NB), blk, 0, stream>>>(
      CATF, WQ, nullptr, nullptr, QT1H);
  dw3x3h_k<<<dim3(NB * C1 * (NPIX / 8) / 256), blk, 0, stream>>>(QT1H, qd_w, QbH, C1);

  // offset head (fp16 single-product MFMA)
  // k2: 64-px tile (like k3's measured optimum); 61 x-blocks, no swizzle (61 % 8 != 0)
  convh_k<64, 128, 2, 4, 0, 62, 62, 64, 64, 0, 256, 256, false, true, false>
      <<<dim3(61, 8, NB), blk, 0, stream>>>(PH, W2K2, nullptr, nullptr, nullptr,
                                            A2, (size_t)NB * 3844 * C2, nullptr);
  // k3: 64-px tile (4 blocks/CU) + XCD swizzle
  convh_k<64, 128, 2, 1, 4, 128, 128, 128, 128, 1, 256, 256, true, false, true>
      <<<dim3(256, 2, NB), blk, 0, stream>>>(CATF, W2K3, y, x, A2, nullptr, 0, OUT3);
  convh_k<128, 32, 1, 8, 0, 128, 128, 128, 128, 1, 18, 32, false, false, true>
      <<<dim3(128, 8, NB), blk, 0, stream>>>(OUT3, W2K4, nullptr, nullptr, nullptr,
                                             OF8P, (size_t)NB * 18 * NPIX, nullptr);
  reduceN_k<8><<<dim3((NB * 18 * NPIX / 4 + 255) / 256), blk, 0, stream>>>(
      OF8P, OFFS, NB * 18 * NPIX / 4);

  // deformable alignment + pw 1x1
  dgemm_k<<<dim3(NPIX / 128, NG, NB), blk, 0, stream>>>(CATF, OFFS, WD, dcn_b, FEAT);
  gemm1x1_k<C1, 0, true, 1><<<dim3(NPIX / 128, 1, NB), blk, 0, stream>>>(
      FEAT, WPW, pw_b, nullptr, AL);

  // kv path
  gemm1x1_k<C1, 0, false, 2><<<dim3(NPIX / 128, 2, NB), blk, 0, stream>>>(
      AL, WKV, nullptr, nullptr, KV1H);
  dw3x3h_k<<<dim3(NB * C2 * (NPIX / 8) / 256), blk, 0, stream>>>(KV1H, kvd_w, KVbH, C2);

  // attention
  gram_k<<<dim3(8, NHEADS, NB), blk, 0, stream>>>(QbH, KVbH, SACC, QSS, KSS);
  attnout_k<<<dim3(NPIX / 256, NHEADS, NB), blk, 0, stream>>>(SACC, QSS, KSS, temperature, KVbH, AO);
  gemm1x1_k<C1, 0, false, 0><<<dim3(NPIX / 128, 1, NB), blk, 0, stream>>>(
      AO, WPJ, nullptr, out, nullptr);
}